// Round 2
// baseline (964.085 us; speedup 1.0000x reference)
//
#include <hip/hip_runtime.h>
#include <math.h>

#define NN 100000
#define EE 1600000
#define ETOT 1700000
#define MM 20000
#define GG 512

static constexpr int NB_N256 = (NN + 255) / 256;    // 391
static constexpr int NB_E256 = (ETOT + 255) / 256;  // 6641
static constexpr int NB_AGG  = NN / 32;             // 3125

// small-buffer layout (float indices)
#define SM_MEAN 0
#define SM_WEA 16
#define SM_VS4 272
#define SM_VD4 400
#define SM_SELF 528   // 4 x u64 self-loop logit packs (8 floats)
#define SM_W4P 536
#define SM_TOTAL 8728

typedef unsigned long long ull;

__device__ __forceinline__ unsigned short f2bf(float f) {
  unsigned int u = __float_as_uint(f);
  u += 0x7fffu + ((u >> 16) & 1u);
  return (unsigned short)(u >> 16);
}
__device__ __forceinline__ float bf2f(unsigned int h) {
  return __uint_as_float(h << 16);
}
__device__ __forceinline__ float lrelu(float v, float s) { return v > 0.f ? v : s * v; }

// ---- CSR: degree count ----
__global__ __launch_bounds__(256) void k_count(const int* __restrict__ ei,
                                               int* __restrict__ counts) {
  int e = blockIdx.x * 256 + threadIdx.x;
  if (e >= ETOT) return;
  int dst = (e < EE) ? ei[EE + e] : (e - EE);
  atomicAdd(&counts[dst], 1);
}

// ---- 3-phase exclusive scan over N ----
__global__ __launch_bounds__(256) void k_scan1(const int* __restrict__ counts,
                                               int* __restrict__ excl,
                                               int* __restrict__ bsum) {
  __shared__ int s[256];
  int t = threadIdx.x, i = blockIdx.x * 256 + t;
  int v = (i < NN) ? counts[i] : 0;
  s[t] = v;
  __syncthreads();
  for (int off = 1; off < 256; off <<= 1) {
    int x = (t >= off) ? s[t - off] : 0;
    __syncthreads();
    s[t] += x;
    __syncthreads();
  }
  if (i < NN) excl[i] = s[t] - v;
  if (t == 255) bsum[blockIdx.x] = s[255];
}

__global__ __launch_bounds__(512) void k_scan2(int* __restrict__ bsum) {
  __shared__ int s[512];
  int t = threadIdx.x;
  int v = (t < NB_N256) ? bsum[t] : 0;
  s[t] = v;
  __syncthreads();
  for (int off = 1; off < 512; off <<= 1) {
    int x = (t >= off) ? s[t - off] : 0;
    __syncthreads();
    s[t] += x;
    __syncthreads();
  }
  if (t < NB_N256) bsum[t] = s[t] - v;
}

__global__ __launch_bounds__(256) void k_scan3(int* __restrict__ row_off,
                                               int* __restrict__ cursor,
                                               const int* __restrict__ bsum) {
  int i = blockIdx.x * 256 + threadIdx.x;
  if (i < NN) {
    int r = row_off[i] + bsum[blockIdx.x];
    row_off[i] = r;
    cursor[i] = r;
  }
  if (i == 0) row_off[NN] = ETOT;
}

// ---- precompute reduced weights ----
__global__ __launch_bounds__(256) void k_pre(
    float* __restrict__ sm, const float* __restrict__ We1, const float* __restrict__ We2,
    const float* __restrict__ We3, const float* __restrict__ We4,
    const float* __restrict__ ae1, const float* __restrict__ ae2,
    const float* __restrict__ ae3, const float* __restrict__ ae4,
    const float* __restrict__ as4, const float* __restrict__ ad4,
    const float* __restrict__ W4) {
  int t = threadIdx.x;
  // Wea[l][d][h] = sum_c We_l[d, h*C+c] * ae_l[h,c]
  {
    int l = t >> 6, d = (t >> 2) & 15, h = t & 3;
    const float* We = (l == 0) ? We1 : (l == 1) ? We2 : (l == 2) ? We3 : We4;
    const float* ae = (l == 0) ? ae1 : (l == 1) ? ae2 : (l == 2) ? ae3 : ae4;
    int C = (l == 3) ? 64 : 8;
    float s = 0.f;
    for (int c = 0; c < C; c++) s += We[d * (4 * C) + h * C + c] * ae[h * C + c];
    sm[SM_WEA + l * 64 + d * 4 + h] = s;
  }
  // Vs4/Vd4 [32][4]
  if (t < 128) {
    int k = t >> 2, h = t & 3;
    float s1 = 0.f, s2 = 0.f;
    for (int c = 0; c < 64; c++) {
      float w = W4[k * 256 + h * 64 + c];
      s1 += w * as4[h * 64 + c];
      s2 += w * ad4[h * 64 + c];
    }
    sm[SM_VS4 + t] = s1;
    sm[SM_VD4 + t] = s2;
  }
  // W4p[h*32+k][c] = 0.25 * W4[k, h*64+c]
  for (int i = t; i < 8192; i += 256) {
    int row = i >> 6, c = i & 63;
    int h = row >> 5, k = row & 31;
    sm[SM_W4P + i] = 0.25f * W4[k * 256 + h * 64 + c];
  }
}

// ---- edge-order attention logits (coalesced) + fused ea-mean reduction ----
__global__ __launch_bounds__(256) void k_aecomp(const float* __restrict__ ea,
                                                float* __restrict__ sm,
                                                ull* __restrict__ aepack) {
  __shared__ float sWea[256];
  __shared__ float lsum[16];
  int t = threadIdx.x;
  sWea[t] = sm[SM_WEA + t];
  if (t < 16) lsum[t] = 0.f;
  __syncthreads();
  float acc16[16];
#pragma unroll
  for (int d = 0; d < 16; d++) acc16[d] = 0.f;
  for (int e = blockIdx.x * 256 + t; e < EE; e += gridDim.x * 256) {
    const float4* p = (const float4*)(ea + (size_t)e * 16);
    float4 v0 = p[0], v1 = p[1], v2 = p[2], v3 = p[3];
    float eav[16] = {v0.x, v0.y, v0.z, v0.w, v1.x, v1.y, v1.z, v1.w,
                     v2.x, v2.y, v2.z, v2.w, v3.x, v3.y, v3.z, v3.w};
#pragma unroll
    for (int d = 0; d < 16; d++) acc16[d] += eav[d];
#pragma unroll
    for (int l = 0; l < 4; l++) {
      ull pk = 0;
#pragma unroll
      for (int h = 0; h < 4; h++) {
        float s = 0.f;
#pragma unroll
        for (int d = 0; d < 16; d++) s += eav[d] * sWea[l * 64 + d * 4 + h];
        pk |= (ull)f2bf(s) << (16 * h);
      }
      aepack[(size_t)l * EE + e] = pk;
    }
  }
  // wave butterfly reduce the 16 dim-sums, then block LDS, then global atomics
#pragma unroll
  for (int d = 0; d < 16; d++) {
    float v = acc16[d];
    for (int m = 1; m < 64; m <<= 1) v += __shfl_xor(v, m, 64);
    acc16[d] = v;
  }
  if ((t & 63) == 0) {
#pragma unroll
    for (int d = 0; d < 16; d++) atomicAdd(&lsum[d], acc16[d]);
  }
  __syncthreads();
  if (t < 16) atomicAdd(&sm[SM_MEAN + t], lsum[t]);
}

// ---- finalize mean, compute the shared self-loop logit pack per layer ----
__global__ __launch_bounds__(64) void k_selfpack(float* __restrict__ sm) {
  int t = threadIdx.x;
  if (t < 16) sm[SM_MEAN + t] *= (1.f / EE);
  __syncthreads();
  if (t < 4) {
    ull pk = 0;
    for (int h = 0; h < 4; h++) {
      float s = 0.f;
      for (int d = 0; d < 16; d++) s += sm[SM_MEAN + d] * sm[SM_WEA + t * 64 + d * 4 + h];
      pk |= (ull)f2bf(s) << (16 * h);
    }
    ((ull*)(sm + SM_SELF))[t] = pk;
  }
}

// ---- CSR fill: one scattered 8B store per edge ----
__global__ __launch_bounds__(256) void k_fill_se(const int* __restrict__ ei,
                                                 int* __restrict__ cursor,
                                                 int2* __restrict__ csr_se) {
  int e = blockIdx.x * 256 + threadIdx.x;
  if (e >= ETOT) return;
  int src, dst;
  if (e < EE) {
    src = ei[e];
    dst = ei[EE + e];
  } else {
    src = dst = e - EE;
  }
  int pos = atomicAdd(&cursor[dst], 1);
  csr_se[pos] = make_int2(src, e);
}

// ---- node transform: hx = in@W (bf16 out), alpha_src/dst reductions ----
template <int DIN>
__global__ __launch_bounds__(256) void k_t(const float* __restrict__ in,
                                           const float* __restrict__ W,
                                           const float* __restrict__ a_s,
                                           const float* __restrict__ a_d,
                                           unsigned short* __restrict__ hxb,
                                           float* __restrict__ ssrc,
                                           float* __restrict__ sdst) {
  __shared__ float4 sW[DIN * 8];
  __shared__ float sas[32], sad[32];
  int t = threadIdx.x;
  for (int i = t; i < DIN * 8; i += 256) sW[i] = ((const float4*)W)[i];
  if (t < 32) { sas[t] = a_s[t]; sad[t] = a_d[t]; }
  __syncthreads();
  int n = blockIdx.x * 256 + t;
  if (n >= NN) return;
  float acc[32];
#pragma unroll
  for (int j = 0; j < 32; j++) acc[j] = 0.f;
  const float* xr = in + (size_t)n * DIN;
  for (int k = 0; k < DIN; k += 4) {
    float4 xv = *(const float4*)(xr + k);
    float xa[4] = {xv.x, xv.y, xv.z, xv.w};
#pragma unroll
    for (int kk = 0; kk < 4; kk++) {
#pragma unroll
      for (int j4 = 0; j4 < 8; j4++) {
        float4 ww = sW[(k + kk) * 8 + j4];
        acc[j4 * 4 + 0] += xa[kk] * ww.x;
        acc[j4 * 4 + 1] += xa[kk] * ww.y;
        acc[j4 * 4 + 2] += xa[kk] * ww.z;
        acc[j4 * 4 + 3] += xa[kk] * ww.w;
      }
    }
  }
  float ssum[4], dsum[4];
#pragma unroll
  for (int h = 0; h < 4; h++) {
    float s = 0.f, d = 0.f;
#pragma unroll
    for (int c = 0; c < 8; c++) {
      s += acc[h * 8 + c] * sas[h * 8 + c];
      d += acc[h * 8 + c] * sad[h * 8 + c];
    }
    ssum[h] = s;
    dsum[h] = d;
  }
  unsigned int up[16];
#pragma unroll
  for (int i = 0; i < 16; i++)
    up[i] = (unsigned)f2bf(acc[2 * i]) | ((unsigned)f2bf(acc[2 * i + 1]) << 16);
  uint4* ho = (uint4*)(hxb + (size_t)n * 32);
  ho[0] = make_uint4(up[0], up[1], up[2], up[3]);
  ho[1] = make_uint4(up[4], up[5], up[6], up[7]);
  ho[2] = make_uint4(up[8], up[9], up[10], up[11]);
  ho[3] = make_uint4(up[12], up[13], up[14], up[15]);
  ((float4*)ssrc)[n] = make_float4(ssum[0], ssum[1], ssum[2], ssum[3]);
  ((float4*)sdst)[n] = make_float4(dsum[0], dsum[1], dsum[2], dsum[3]);
}

// ---- layer-4 attention reductions + bf16 copy of h3 ----
__global__ __launch_bounds__(256) void k_t4(const float* __restrict__ h3,
                                            const float* __restrict__ sm,
                                            unsigned short* __restrict__ h3b,
                                            float* __restrict__ ssrc,
                                            float* __restrict__ sdst) {
  __shared__ float sVs[128], sVd[128];
  int t = threadIdx.x;
  if (t < 128) { sVs[t] = sm[SM_VS4 + t]; sVd[t] = sm[SM_VD4 + t]; }
  __syncthreads();
  int n = blockIdx.x * 256 + t;
  if (n >= NN) return;
  const float* r = h3 + (size_t)n * 32;
  float v[32];
#pragma unroll
  for (int k = 0; k < 32; k++) v[k] = r[k];
  float s0 = 0, s1 = 0, s2 = 0, s3 = 0, d0 = 0, d1 = 0, d2 = 0, d3 = 0;
#pragma unroll
  for (int k = 0; k < 32; k++) {
    s0 += v[k] * sVs[k * 4 + 0]; s1 += v[k] * sVs[k * 4 + 1];
    s2 += v[k] * sVs[k * 4 + 2]; s3 += v[k] * sVs[k * 4 + 3];
    d0 += v[k] * sVd[k * 4 + 0]; d1 += v[k] * sVd[k * 4 + 1];
    d2 += v[k] * sVd[k * 4 + 2]; d3 += v[k] * sVd[k * 4 + 3];
  }
  unsigned int up[16];
#pragma unroll
  for (int i = 0; i < 16; i++)
    up[i] = (unsigned)f2bf(v[2 * i]) | ((unsigned)f2bf(v[2 * i + 1]) << 16);
  uint4* ho = (uint4*)(h3b + (size_t)n * 32);
  ho[0] = make_uint4(up[0], up[1], up[2], up[3]);
  ho[1] = make_uint4(up[4], up[5], up[6], up[7]);
  ho[2] = make_uint4(up[8], up[9], up[10], up[11]);
  ho[3] = make_uint4(up[12], up[13], up[14], up[15]);
  ((float4*)ssrc)[n] = make_float4(s0, s1, s2, s3);
  ((float4*)sdst)[n] = make_float4(d0, d1, d2, d3);
}

// ---- layers 1-3 aggregation: 8 lanes/node, online softmax, fused epilogue ----
__global__ __launch_bounds__(256) void k_agg(const int* __restrict__ row_off,
                                             const int2* __restrict__ csr_se,
                                             const ull* __restrict__ aepack_l,
                                             const ull* __restrict__ selfp,
                                             const unsigned short* __restrict__ hxb,
                                             const float* __restrict__ ssrc,
                                             const float* __restrict__ sdst,
                                             const float* __restrict__ bias,
                                             float* __restrict__ outp) {
  int t = threadIdx.x;
  int g = t >> 3, j = t & 7, h = j >> 1;
  int n = blockIdx.x * 32 + g;
  if (n >= NN) return;
  ull spk = *selfp;
  float sd = sdst[n * 4 + h];
  int e0 = row_off[n], e1 = row_off[n + 1];
  float m = -1e30f, den = 0.f;
  float4 acc = make_float4(0.f, 0.f, 0.f, 0.f);
  for (int e = e0; e < e1; ++e) {
    int2 se = csr_se[e];
    int src = se.x, eid = se.y;
    ull pk = (eid < EE) ? aepack_l[eid] : spk;
    float ae = bf2f((unsigned int)(unsigned short)(pk >> (16 * h)));
    float al = ssrc[src * 4 + h] + sd + ae;
    al = lrelu(al, 0.2f);
    uint2 u = *(const uint2*)(hxb + (size_t)src * 32 + (j << 2));
    float nm = fmaxf(m, al);
    float c1 = __expf(m - nm);
    float p = __expf(al - nm);
    den = den * c1 + p;
    acc.x = acc.x * c1 + p * bf2f(u.x & 0xffffu);
    acc.y = acc.y * c1 + p * bf2f(u.x >> 16);
    acc.z = acc.z * c1 + p * bf2f(u.y & 0xffffu);
    acc.w = acc.w * c1 + p * bf2f(u.y >> 16);
    m = nm;
  }
  float inv = 1.f / (den + 1e-16f);
  float4 b = *(const float4*)(bias + (j << 2));
  float4 o;
  o.x = lrelu(acc.x * inv + b.x, 0.01f);
  o.y = lrelu(acc.y * inv + b.y, 0.01f);
  o.z = lrelu(acc.z * inv + b.z, 0.01f);
  o.w = lrelu(acc.w * inv + b.w, 0.01f);
  *(float4*)(outp + (size_t)n * 32 + (j << 2)) = o;
}

// ---- layer-4 aggregation: aggregate h3 per head (agg-then-transform), bf16 out ----
__global__ __launch_bounds__(256) void k_agg4(const int* __restrict__ row_off,
                                              const int2* __restrict__ csr_se,
                                              const ull* __restrict__ aepack_l,
                                              const ull* __restrict__ selfp,
                                              const unsigned short* __restrict__ h3b,
                                              const float* __restrict__ ssrc,
                                              const float* __restrict__ sdst,
                                              unsigned short* __restrict__ aggb) {
  int t = threadIdx.x;
  int g = t >> 3, j = t & 7;
  int n = blockIdx.x * 32 + g;
  if (n >= NN) return;
  ull spk = *selfp;
  float4 sdv = ((const float4*)sdst)[n];
  float sda[4] = {sdv.x, sdv.y, sdv.z, sdv.w};
  int e0 = row_off[n], e1 = row_off[n + 1];
  float m[4], den[4];
  float4 acc[4];
#pragma unroll
  for (int h = 0; h < 4; h++) {
    m[h] = -1e30f;
    den[h] = 0.f;
    acc[h] = make_float4(0.f, 0.f, 0.f, 0.f);
  }
  for (int e = e0; e < e1; ++e) {
    int2 se = csr_se[e];
    int src = se.x, eid = se.y;
    ull pk = (eid < EE) ? aepack_l[eid] : spk;
    float4 ssv = ((const float4*)ssrc)[src];
    float ssa[4] = {ssv.x, ssv.y, ssv.z, ssv.w};
    uint2 u = *(const uint2*)(h3b + (size_t)src * 32 + (j << 2));
    float hx0 = bf2f(u.x & 0xffffu), hx1 = bf2f(u.x >> 16);
    float hx2 = bf2f(u.y & 0xffffu), hx3 = bf2f(u.y >> 16);
#pragma unroll
    for (int h = 0; h < 4; h++) {
      float al = ssa[h] + sda[h] + bf2f((unsigned int)(unsigned short)(pk >> (16 * h)));
      al = lrelu(al, 0.2f);
      float nm = fmaxf(m[h], al);
      float c1 = __expf(m[h] - nm);
      float p = __expf(al - nm);
      den[h] = den[h] * c1 + p;
      acc[h].x = acc[h].x * c1 + p * hx0;
      acc[h].y = acc[h].y * c1 + p * hx1;
      acc[h].z = acc[h].z * c1 + p * hx2;
      acc[h].w = acc[h].w * c1 + p * hx3;
      m[h] = nm;
    }
  }
#pragma unroll
  for (int h = 0; h < 4; h++) {
    float inv = 1.f / (den[h] + 1e-16f);
    unsigned int u0 = (unsigned)f2bf(acc[h].x * inv) | ((unsigned)f2bf(acc[h].y * inv) << 16);
    unsigned int u1 = (unsigned)f2bf(acc[h].z * inv) | ((unsigned)f2bf(acc[h].w * inv) << 16);
    *(uint2*)(aggb + (size_t)n * 128 + h * 32 + (j << 2)) = make_uint2(u0, u1);
  }
}

// ---- layer-4 epilogue: [N,128](bf16) @ W4p[128,64] + b4, lrelu -> h4 ----
__global__ __launch_bounds__(256) void k_epi4(const unsigned short* __restrict__ aggb,
                                              const float* __restrict__ sm,
                                              const float* __restrict__ b4,
                                              float* __restrict__ h4) {
  __shared__ float4 sW[2048];
  __shared__ float sb[64];
  int t = threadIdx.x;
  for (int i = t; i < 2048; i += 256) sW[i] = ((const float4*)(sm + SM_W4P))[i];
  if (t < 64) sb[t] = b4[t];
  __syncthreads();
  int n = blockIdx.x * 256 + t;
  if (n >= NN) return;
  float acc[64];
#pragma unroll
  for (int j = 0; j < 64; j++) acc[j] = 0.f;
  const unsigned short* r = aggb + (size_t)n * 128;
  for (int k = 0; k < 128; k += 4) {
    uint2 u = *(const uint2*)(r + k);
    float va[4] = {bf2f(u.x & 0xffffu), bf2f(u.x >> 16), bf2f(u.y & 0xffffu),
                   bf2f(u.y >> 16)};
#pragma unroll
    for (int kk = 0; kk < 4; kk++) {
#pragma unroll
      for (int j4 = 0; j4 < 16; j4++) {
        float4 wv = sW[(k + kk) * 16 + j4];
        acc[j4 * 4 + 0] += va[kk] * wv.x;
        acc[j4 * 4 + 1] += va[kk] * wv.y;
        acc[j4 * 4 + 2] += va[kk] * wv.z;
        acc[j4 * 4 + 3] += va[kk] * wv.w;
      }
    }
  }
  float* o = h4 + (size_t)n * 64;
#pragma unroll
  for (int j4 = 0; j4 < 16; j4++) {
    float4 ov;
    ov.x = lrelu(acc[j4 * 4 + 0] + sb[j4 * 4 + 0], 0.01f);
    ov.y = lrelu(acc[j4 * 4 + 1] + sb[j4 * 4 + 1], 0.01f);
    ov.z = lrelu(acc[j4 * 4 + 2] + sb[j4 * 4 + 2], 0.01f);
    ov.w = lrelu(acc[j4 * 4 + 3] + sb[j4 * 4 + 3], 0.01f);
    ((float4*)o)[j4] = ov;
  }
}

// ---- pooling ----
__global__ __launch_bounds__(256) void k_pool1(const float* __restrict__ h4,
                                               const int* __restrict__ sidx,
                                               float* __restrict__ pool1) {
  int i = blockIdx.x * 256 + threadIdx.x;
  if (i >= NN * 64) return;
  int n = i >> 6, c = i & 63;
  atomicAdd(&pool1[(size_t)sidx[n] * 64 + c], h4[i]);
}

__global__ __launch_bounds__(256) void k_pool2(const float* __restrict__ pool1,
                                               const float* __restrict__ snorm,
                                               const int* __restrict__ nodes,
                                               float* __restrict__ pool2) {
  int i = blockIdx.x * 256 + threadIdx.x;
  if (i >= MM * 64) return;
  int mi = i >> 6, c = i & 63;
  float v = pool1[i] / snorm[mi];
  atomicAdd(&pool2[(size_t)nodes[mi] * 64 + c], v);
}

// ---- final head: one wave per group ----
__global__ __launch_bounds__(64) void k_final(const float* __restrict__ pool2,
                                              const float* __restrict__ h4,
                                              const int* __restrict__ dvi,
                                              const float* __restrict__ Wp,
                                              const float* __restrict__ Wt,
                                              const float* __restrict__ Wo,
                                              const float* __restrict__ bo,
                                              float* __restrict__ out) {
  __shared__ float p[64], tt[64];
  int gI = blockIdx.x, j = threadIdx.x;
  p[j] = pool2[gI * 64 + j];
  tt[j] = h4[(size_t)dvi[gI] * 64 + j];
  __syncthreads();
  float f1 = 0.f, f2 = 0.f;
#pragma unroll 8
  for (int c = 0; c < 64; c++) {
    f1 += p[c] * Wp[c * 64 + j];
    f2 += tt[c] * Wt[c * 64 + j];
  }
  f1 = lrelu(f1, 0.01f);
  f2 = lrelu(f2, 0.01f);
  float v = f1 * Wo[j] + f2 * Wo[64 + j];
  for (int off = 32; off > 0; off >>= 1) v += __shfl_down(v, off, 64);
  if (j == 0) out[gI] = v + bo[0];
}

extern "C" void kernel_launch(void* const* d_in, const int* in_sizes, int n_in,
                              void* d_out, int out_size, void* d_ws, size_t ws_size,
                              hipStream_t stream) {
  const float* x = (const float*)d_in[0];
  const int* ei = (const int*)d_in[1];
  const float* ea = (const float*)d_in[2];
  const int* sidx = (const int*)d_in[3];
  const float* snorm = (const float*)d_in[4];
  const int* nodes = (const int*)d_in[5];
  const int* dvi = (const int*)d_in[6];
  const float* W1 = (const float*)d_in[7];
  const float* as1 = (const float*)d_in[9];
  const float* ad1 = (const float*)d_in[10];
  const float* b1 = (const float*)d_in[12];
  const float* W2 = (const float*)d_in[13];
  const float* as2 = (const float*)d_in[15];
  const float* ad2 = (const float*)d_in[16];
  const float* b2 = (const float*)d_in[18];
  const float* W3 = (const float*)d_in[19];
  const float* as3 = (const float*)d_in[21];
  const float* ad3 = (const float*)d_in[22];
  const float* b3 = (const float*)d_in[24];
  const float* b4 = (const float*)d_in[30];
  const float* Wp = (const float*)d_in[31];
  const float* Wt = (const float*)d_in[32];
  const float* Wo = (const float*)d_in[33];
  const float* bo = (const float*)d_in[34];
  float* out = (float*)d_out;

  char* w = (char*)d_ws;
  size_t off = 0;
  auto take = [&](size_t bytes) -> char* {
    char* p = w + off;
    off = (off + bytes + 255) & ~(size_t)255;
    return p;
  };
  int* row_off = (int*)take((size_t)(NN + 1) * 4);
  int* cursor = (int*)take((size_t)NN * 4);
  int* bsum = (int*)take(512 * 4);
  float* sm = (float*)take(SM_TOTAL * 4);
  int2* csr_se = (int2*)take((size_t)ETOT * 8);
  ull* aepack = (ull*)take((size_t)EE * 4 * 8);
  unsigned short* hxb = (unsigned short*)take((size_t)NN * 32 * 2);
  unsigned short* h3b = (unsigned short*)take((size_t)NN * 32 * 2);
  float* ssrc = (float*)take((size_t)NN * 4 * 4);
  float* sdst = (float*)take((size_t)NN * 4 * 4);
  float* bufA = (float*)take((size_t)NN * 32 * 4);
  float* bufB = (float*)take((size_t)NN * 32 * 4);
  float* h4 = (float*)take((size_t)NN * 64 * 4);
  unsigned short* aggb = (unsigned short*)take((size_t)NN * 128 * 2);
  float* pool1 = (float*)take((size_t)MM * 64 * 4);
  float* pool2 = (float*)take((size_t)GG * 64 * 4);
  if (off > ws_size) return;  // workspace too small -> visible validation failure

  hipMemsetAsync(cursor, 0, (size_t)NN * 4, stream);
  hipMemsetAsync(sm, 0, 64, stream);
  hipMemsetAsync(pool1, 0, (size_t)MM * 64 * 4, stream);
  hipMemsetAsync(pool2, 0, (size_t)GG * 64 * 4, stream);

  k_count<<<NB_E256, 256, 0, stream>>>(ei, cursor);
  k_scan1<<<NB_N256, 256, 0, stream>>>(cursor, row_off, bsum);
  k_scan2<<<1, 512, 0, stream>>>(bsum);
  k_scan3<<<NB_N256, 256, 0, stream>>>(row_off, cursor, bsum);
  k_pre<<<1, 256, 0, stream>>>(sm, (const float*)d_in[8], (const float*)d_in[14],
                               (const float*)d_in[20], (const float*)d_in[26],
                               (const float*)d_in[11], (const float*)d_in[17],
                               (const float*)d_in[23], (const float*)d_in[29],
                               (const float*)d_in[27], (const float*)d_in[28],
                               (const float*)d_in[25]);
  k_aecomp<<<2048, 256, 0, stream>>>(ea, sm, aepack);
  k_selfpack<<<1, 64, 0, stream>>>(sm);
  k_fill_se<<<NB_E256, 256, 0, stream>>>(ei, cursor, csr_se);

  const ull* selfp = (const ull*)(sm + SM_SELF);
  // layer 1
  k_t<64><<<NB_N256, 256, 0, stream>>>(x, W1, as1, ad1, hxb, ssrc, sdst);
  k_agg<<<NB_AGG, 256, 0, stream>>>(row_off, csr_se, aepack, selfp, hxb, ssrc, sdst, b1,
                                    bufA);
  // layer 2
  k_t<32><<<NB_N256, 256, 0, stream>>>(bufA, W2, as2, ad2, hxb, ssrc, sdst);
  k_agg<<<NB_AGG, 256, 0, stream>>>(row_off, csr_se, aepack + (size_t)EE, selfp + 1, hxb,
                                    ssrc, sdst, b2, bufB);
  // layer 3
  k_t<32><<<NB_N256, 256, 0, stream>>>(bufB, W3, as3, ad3, hxb, ssrc, sdst);
  k_agg<<<NB_AGG, 256, 0, stream>>>(row_off, csr_se, aepack + 2 * (size_t)EE, selfp + 2,
                                    hxb, ssrc, sdst, b3, bufA);
  // layer 4
  k_t4<<<NB_N256, 256, 0, stream>>>(bufA, sm, h3b, ssrc, sdst);
  k_agg4<<<NB_AGG, 256, 0, stream>>>(row_off, csr_se, aepack + 3 * (size_t)EE, selfp + 3,
                                     h3b, ssrc, sdst, aggb);
  k_epi4<<<NB_N256, 256, 0, stream>>>(aggb, sm, b4, h4);

  // pooling head
  k_pool1<<<(NN * 64) / 256, 256, 0, stream>>>(h4, sidx, pool1);
  k_pool2<<<(MM * 64) / 256, 256, 0, stream>>>(pool1, snorm, nodes, pool2);
  k_final<<<GG, 64, 0, stream>>>(pool2, h4, dvi, Wp, Wt, Wo, bo, out);
}

// Round 3
// 832.761 us; speedup vs baseline: 1.1577x; 1.1577x over previous
//
#include <hip/hip_runtime.h>
#include <math.h>

#define NN 100000
#define EE 1600000
#define ETOT 1700000
#define MM 20000
#define GG 512

#define NBUCK 782   // ceil(100000/128)
#define NB1 256     // phase-1 blocks (must match k_bscan_a's 256 threads)

static constexpr int NB_N256 = (NN + 255) / 256;    // 391
static constexpr int NB_AGG  = NN / 32;             // 3125

// small-buffer layout (float indices)
#define SM_MEAN 0
#define SM_WEA 16
#define SM_VS4 272
#define SM_VD4 400
#define SM_SELF 528   // 4 x u64 self-loop logit packs (8 floats)
#define SM_W4P 536
#define SM_TOTAL 8728

typedef unsigned long long ull;

__device__ __forceinline__ unsigned short f2bf(float f) {
  unsigned int u = __float_as_uint(f);
  u += 0x7fffu + ((u >> 16) & 1u);
  return (unsigned short)(u >> 16);
}
__device__ __forceinline__ float bf2f(unsigned int h) {
  return __uint_as_float(h << 16);
}
__device__ __forceinline__ float lrelu(float v, float s) { return v > 0.f ? v : s * v; }

// ---- precompute reduced weights ----
__global__ __launch_bounds__(256) void k_pre(
    float* __restrict__ sm, const float* __restrict__ We1, const float* __restrict__ We2,
    const float* __restrict__ We3, const float* __restrict__ We4,
    const float* __restrict__ ae1, const float* __restrict__ ae2,
    const float* __restrict__ ae3, const float* __restrict__ ae4,
    const float* __restrict__ as4, const float* __restrict__ ad4,
    const float* __restrict__ W4) {
  int t = threadIdx.x;
  {
    int l = t >> 6, d = (t >> 2) & 15, h = t & 3;
    const float* We = (l == 0) ? We1 : (l == 1) ? We2 : (l == 2) ? We3 : We4;
    const float* ae = (l == 0) ? ae1 : (l == 1) ? ae2 : (l == 2) ? ae3 : ae4;
    int C = (l == 3) ? 64 : 8;
    float s = 0.f;
    for (int c = 0; c < C; c++) s += We[d * (4 * C) + h * C + c] * ae[h * C + c];
    sm[SM_WEA + l * 64 + d * 4 + h] = s;
  }
  if (t < 128) {
    int k = t >> 2, h = t & 3;
    float s1 = 0.f, s2 = 0.f;
    for (int c = 0; c < 64; c++) {
      float w = W4[k * 256 + h * 64 + c];
      s1 += w * as4[h * 64 + c];
      s2 += w * ad4[h * 64 + c];
    }
    sm[SM_VS4 + t] = s1;
    sm[SM_VD4 + t] = s2;
  }
  for (int i = t; i < 8192; i += 256) {
    int row = i >> 6, c = i & 63;
    int h = row >> 5, k = row & 31;
    sm[SM_W4P + i] = 0.25f * W4[k * 256 + h * 64 + c];
  }
}

// ---- edge-order attention logits (coalesced, AoS per-edge) + fused ea-mean ----
__global__ __launch_bounds__(256) void k_aecomp(const float* __restrict__ ea,
                                                float* __restrict__ sm,
                                                ull* __restrict__ aepack4) {
  __shared__ float sWea[256];
  __shared__ float lsum[16];
  int t = threadIdx.x;
  sWea[t] = sm[SM_WEA + t];
  if (t < 16) lsum[t] = 0.f;
  __syncthreads();
  float acc16[16];
#pragma unroll
  for (int d = 0; d < 16; d++) acc16[d] = 0.f;
  for (int e = blockIdx.x * 256 + t; e < EE; e += gridDim.x * 256) {
    const float4* p = (const float4*)(ea + (size_t)e * 16);
    float4 v0 = p[0], v1 = p[1], v2 = p[2], v3 = p[3];
    float eav[16] = {v0.x, v0.y, v0.z, v0.w, v1.x, v1.y, v1.z, v1.w,
                     v2.x, v2.y, v2.z, v2.w, v3.x, v3.y, v3.z, v3.w};
#pragma unroll
    for (int d = 0; d < 16; d++) acc16[d] += eav[d];
#pragma unroll
    for (int l = 0; l < 4; l++) {
      ull pk = 0;
#pragma unroll
      for (int h = 0; h < 4; h++) {
        float s = 0.f;
#pragma unroll
        for (int d = 0; d < 16; d++) s += eav[d] * sWea[l * 64 + d * 4 + h];
        pk |= (ull)f2bf(s) << (16 * h);
      }
      aepack4[(size_t)e * 4 + l] = pk;
    }
  }
#pragma unroll
  for (int d = 0; d < 16; d++) {
    float v = acc16[d];
    for (int m = 1; m < 64; m <<= 1) v += __shfl_xor(v, m, 64);
    acc16[d] = v;
  }
  if ((t & 63) == 0) {
#pragma unroll
    for (int d = 0; d < 16; d++) atomicAdd(&lsum[d], acc16[d]);
  }
  __syncthreads();
  if (t < 16) atomicAdd(&sm[SM_MEAN + t], lsum[t]);
}

// ---- finalize mean, compute the shared self-loop logit pack per layer ----
__global__ __launch_bounds__(64) void k_selfpack(float* __restrict__ sm) {
  int t = threadIdx.x;
  if (t < 16) sm[SM_MEAN + t] *= (1.f / EE);
  __syncthreads();
  if (t < 4) {
    ull pk = 0;
    for (int h = 0; h < 4; h++) {
      float s = 0.f;
      for (int d = 0; d < 16; d++) s += sm[SM_MEAN + d] * sm[SM_WEA + t * 64 + d * 4 + h];
      pk |= (ull)f2bf(s) << (16 * h);
    }
    ((ull*)(sm + SM_SELF))[t] = pk;
  }
}

// ---- sort phase 1: per-block 782-bucket LDS histogram ----
__global__ __launch_bounds__(1024) void k_hist1(const int* __restrict__ ei,
                                                int* __restrict__ blk_cnt) {
  __shared__ int hist[NBUCK];
  int t = threadIdx.x;
  for (int i = t; i < NBUCK; i += 1024) hist[i] = 0;
  __syncthreads();
  for (int e = blockIdx.x * 1024 + t; e < ETOT; e += NB1 * 1024) {
    int dst = (e < EE) ? ei[EE + e] : (e - EE);
    atomicAdd(&hist[dst >> 7], 1);
  }
  __syncthreads();
  for (int i = t; i < NBUCK; i += 1024) blk_cnt[blockIdx.x * NBUCK + i] = hist[i];
}

// ---- scan A: per-bucket exclusive scan over the 256 blocks ----
__global__ __launch_bounds__(256) void k_bscan_a(const int* __restrict__ blk_cnt,
                                                 int* __restrict__ blk_base_T,
                                                 int* __restrict__ bucket_tot) {
  __shared__ int s[256];
  int b = blockIdx.x, t = threadIdx.x;
  int v = blk_cnt[t * NBUCK + b];
  s[t] = v;
  __syncthreads();
  for (int off = 1; off < 256; off <<= 1) {
    int x = (t >= off) ? s[t - off] : 0;
    __syncthreads();
    s[t] += x;
    __syncthreads();
  }
  blk_base_T[b * 256 + t] = s[t] - v;
  if (t == 255) bucket_tot[b] = s[255];
}

// ---- scan B: exclusive scan of bucket totals ----
__global__ __launch_bounds__(1024) void k_bscan_b(const int* __restrict__ bucket_tot,
                                                  int* __restrict__ bucket_base,
                                                  int* __restrict__ row_off) {
  __shared__ int s[1024];
  int t = threadIdx.x;
  int v = (t < NBUCK) ? bucket_tot[t] : 0;
  s[t] = v;
  __syncthreads();
  for (int off = 1; off < 1024; off <<= 1) {
    int x = (t >= off) ? s[t - off] : 0;
    __syncthreads();
    s[t] += x;
    __syncthreads();
  }
  if (t < NBUCK) bucket_base[t] = s[t] - v;
  if (t == 0) {
    bucket_base[NBUCK] = ETOT;
    row_off[NN] = ETOT;
  }
}

// ---- sort phase 1 scatter: (dst,eid) pairs into dense bucket regions ----
__global__ __launch_bounds__(1024) void k_scatter1(const int* __restrict__ ei,
                                                   const int* __restrict__ bucket_base,
                                                   const int* __restrict__ blk_base_T,
                                                   int2* __restrict__ pairs) {
  __shared__ int base[NBUCK];
  __shared__ int rank[NBUCK];
  int t = threadIdx.x, blk = blockIdx.x;
  for (int i = t; i < NBUCK; i += 1024) {
    base[i] = bucket_base[i] + blk_base_T[i * 256 + blk];
    rank[i] = 0;
  }
  __syncthreads();
  for (int e = blk * 1024 + t; e < ETOT; e += NB1 * 1024) {
    int dst = (e < EE) ? ei[EE + e] : (e - EE);
    int bin = dst >> 7;
    int r = atomicAdd(&rank[bin], 1);
    pairs[base[bin] + r] = make_int2(dst, e);
  }
}

// ---- sort phase 2: exact dst order within bucket, fused permute of src+packs ----
__global__ __launch_bounds__(256) void k_sort2(const int2* __restrict__ pairs,
                                               const int* __restrict__ bucket_base,
                                               const int* __restrict__ ei,
                                               const ull* __restrict__ aepack4,
                                               const float* __restrict__ sm,
                                               int* __restrict__ row_off,
                                               int* __restrict__ csr_src,
                                               ull* __restrict__ apc) {
  __shared__ int hist[128];
  __shared__ int scan[128];
  __shared__ int rankv[128];
  __shared__ ull sself[4];
  int b = blockIdx.x, t = threadIdx.x;
  int start = bucket_base[b], end = bucket_base[b + 1];
  if (t < 128) hist[t] = 0;
  if (t < 4) sself[t] = ((const ull*)(sm + SM_SELF))[t];
  __syncthreads();
  for (int i = start + t; i < end; i += 256) atomicAdd(&hist[pairs[i].x & 127], 1);
  __syncthreads();
  if (t < 128) scan[t] = hist[t];
  __syncthreads();
  for (int off = 1; off < 128; off <<= 1) {
    int x = (t >= off && t < 128) ? scan[t - off] : 0;
    __syncthreads();
    if (t < 128) scan[t] += x;
    __syncthreads();
  }
  if (t < 128) {
    int excl = scan[t] - hist[t];
    rankv[t] = excl;
    int dst = b * 128 + t;
    if (dst < NN) row_off[dst] = start + excl;
  }
  __syncthreads();
  for (int i = start + t; i < end; i += 256) {
    int2 pe = pairs[i];
    int bin = pe.x & 127, eid = pe.y;
    int r = atomicAdd(&rankv[bin], 1);
    int pos = start + r;
    int src;
    ull p0, p1, p2, p3;
    if (eid < EE) {
      src = ei[eid];
      const ull* ap = aepack4 + (size_t)eid * 4;
      p0 = ap[0]; p1 = ap[1]; p2 = ap[2]; p3 = ap[3];
    } else {
      src = eid - EE;
      p0 = sself[0]; p1 = sself[1]; p2 = sself[2]; p3 = sself[3];
    }
    csr_src[pos] = src;
    apc[pos] = p0;
    apc[(size_t)ETOT + pos] = p1;
    apc[2 * (size_t)ETOT + pos] = p2;
    apc[3 * (size_t)ETOT + pos] = p3;
  }
}

// ---- node transform: hx = in@W (bf16 out), alpha_src/dst reductions ----
template <int DIN>
__global__ __launch_bounds__(256) void k_t(const float* __restrict__ in,
                                           const float* __restrict__ W,
                                           const float* __restrict__ a_s,
                                           const float* __restrict__ a_d,
                                           unsigned short* __restrict__ hxb,
                                           float* __restrict__ ssrc,
                                           float* __restrict__ sdst) {
  __shared__ float4 sW[DIN * 8];
  __shared__ float sas[32], sad[32];
  int t = threadIdx.x;
  for (int i = t; i < DIN * 8; i += 256) sW[i] = ((const float4*)W)[i];
  if (t < 32) { sas[t] = a_s[t]; sad[t] = a_d[t]; }
  __syncthreads();
  int n = blockIdx.x * 256 + t;
  if (n >= NN) return;
  float acc[32];
#pragma unroll
  for (int j = 0; j < 32; j++) acc[j] = 0.f;
  const float* xr = in + (size_t)n * DIN;
  for (int k = 0; k < DIN; k += 4) {
    float4 xv = *(const float4*)(xr + k);
    float xa[4] = {xv.x, xv.y, xv.z, xv.w};
#pragma unroll
    for (int kk = 0; kk < 4; kk++) {
#pragma unroll
      for (int j4 = 0; j4 < 8; j4++) {
        float4 ww = sW[(k + kk) * 8 + j4];
        acc[j4 * 4 + 0] += xa[kk] * ww.x;
        acc[j4 * 4 + 1] += xa[kk] * ww.y;
        acc[j4 * 4 + 2] += xa[kk] * ww.z;
        acc[j4 * 4 + 3] += xa[kk] * ww.w;
      }
    }
  }
  float ssum[4], dsum[4];
#pragma unroll
  for (int h = 0; h < 4; h++) {
    float s = 0.f, d = 0.f;
#pragma unroll
    for (int c = 0; c < 8; c++) {
      s += acc[h * 8 + c] * sas[h * 8 + c];
      d += acc[h * 8 + c] * sad[h * 8 + c];
    }
    ssum[h] = s;
    dsum[h] = d;
  }
  unsigned int up[16];
#pragma unroll
  for (int i = 0; i < 16; i++)
    up[i] = (unsigned)f2bf(acc[2 * i]) | ((unsigned)f2bf(acc[2 * i + 1]) << 16);
  uint4* ho = (uint4*)(hxb + (size_t)n * 32);
  ho[0] = make_uint4(up[0], up[1], up[2], up[3]);
  ho[1] = make_uint4(up[4], up[5], up[6], up[7]);
  ho[2] = make_uint4(up[8], up[9], up[10], up[11]);
  ho[3] = make_uint4(up[12], up[13], up[14], up[15]);
  ((float4*)ssrc)[n] = make_float4(ssum[0], ssum[1], ssum[2], ssum[3]);
  ((float4*)sdst)[n] = make_float4(dsum[0], dsum[1], dsum[2], dsum[3]);
}

// ---- layer-4 attention reductions + bf16 copy of h3 ----
__global__ __launch_bounds__(256) void k_t4(const float* __restrict__ h3,
                                            const float* __restrict__ sm,
                                            unsigned short* __restrict__ h3b,
                                            float* __restrict__ ssrc,
                                            float* __restrict__ sdst) {
  __shared__ float sVs[128], sVd[128];
  int t = threadIdx.x;
  if (t < 128) { sVs[t] = sm[SM_VS4 + t]; sVd[t] = sm[SM_VD4 + t]; }
  __syncthreads();
  int n = blockIdx.x * 256 + t;
  if (n >= NN) return;
  const float* r = h3 + (size_t)n * 32;
  float v[32];
#pragma unroll
  for (int k = 0; k < 32; k++) v[k] = r[k];
  float s0 = 0, s1 = 0, s2 = 0, s3 = 0, d0 = 0, d1 = 0, d2 = 0, d3 = 0;
#pragma unroll
  for (int k = 0; k < 32; k++) {
    s0 += v[k] * sVs[k * 4 + 0]; s1 += v[k] * sVs[k * 4 + 1];
    s2 += v[k] * sVs[k * 4 + 2]; s3 += v[k] * sVs[k * 4 + 3];
    d0 += v[k] * sVd[k * 4 + 0]; d1 += v[k] * sVd[k * 4 + 1];
    d2 += v[k] * sVd[k * 4 + 2]; d3 += v[k] * sVd[k * 4 + 3];
  }
  unsigned int up[16];
#pragma unroll
  for (int i = 0; i < 16; i++)
    up[i] = (unsigned)f2bf(v[2 * i]) | ((unsigned)f2bf(v[2 * i + 1]) << 16);
  uint4* ho = (uint4*)(h3b + (size_t)n * 32);
  ho[0] = make_uint4(up[0], up[1], up[2], up[3]);
  ho[1] = make_uint4(up[4], up[5], up[6], up[7]);
  ho[2] = make_uint4(up[8], up[9], up[10], up[11]);
  ho[3] = make_uint4(up[12], up[13], up[14], up[15]);
  ((float4*)ssrc)[n] = make_float4(s0, s1, s2, s3);
  ((float4*)sdst)[n] = make_float4(d0, d1, d2, d3);
}

// ---- layers 1-3 aggregation: 8 lanes/node, online softmax, fused epilogue ----
__global__ __launch_bounds__(256) void k_agg(const int* __restrict__ row_off,
                                             const int* __restrict__ csr_src,
                                             const ull* __restrict__ apl,
                                             const unsigned short* __restrict__ hxb,
                                             const float* __restrict__ ssrc,
                                             const float* __restrict__ sdst,
                                             const float* __restrict__ bias,
                                             float* __restrict__ outp) {
  int t = threadIdx.x;
  int g = t >> 3, j = t & 7, h = j >> 1;
  int n = blockIdx.x * 32 + g;
  if (n >= NN) return;
  float sd = sdst[n * 4 + h];
  int e0 = row_off[n], e1 = row_off[n + 1];
  float m = -1e30f, den = 0.f;
  float4 acc = make_float4(0.f, 0.f, 0.f, 0.f);
  for (int e = e0; e < e1; ++e) {
    int src = csr_src[e];
    ull pk = apl[e];
    float ae = bf2f((unsigned int)(unsigned short)(pk >> (16 * h)));
    float al = ssrc[src * 4 + h] + sd + ae;
    al = lrelu(al, 0.2f);
    uint2 u = *(const uint2*)(hxb + (size_t)src * 32 + (j << 2));
    float nm = fmaxf(m, al);
    float c1 = __expf(m - nm);
    float p = __expf(al - nm);
    den = den * c1 + p;
    acc.x = acc.x * c1 + p * bf2f(u.x & 0xffffu);
    acc.y = acc.y * c1 + p * bf2f(u.x >> 16);
    acc.z = acc.z * c1 + p * bf2f(u.y & 0xffffu);
    acc.w = acc.w * c1 + p * bf2f(u.y >> 16);
    m = nm;
  }
  float inv = 1.f / (den + 1e-16f);
  float4 b = *(const float4*)(bias + (j << 2));
  float4 o;
  o.x = lrelu(acc.x * inv + b.x, 0.01f);
  o.y = lrelu(acc.y * inv + b.y, 0.01f);
  o.z = lrelu(acc.z * inv + b.z, 0.01f);
  o.w = lrelu(acc.w * inv + b.w, 0.01f);
  *(float4*)(outp + (size_t)n * 32 + (j << 2)) = o;
}

// ---- layer-4 aggregation: aggregate h3 per head, bf16 out ----
__global__ __launch_bounds__(256) void k_agg4(const int* __restrict__ row_off,
                                              const int* __restrict__ csr_src,
                                              const ull* __restrict__ apl,
                                              const unsigned short* __restrict__ h3b,
                                              const float* __restrict__ ssrc,
                                              const float* __restrict__ sdst,
                                              unsigned short* __restrict__ aggb) {
  int t = threadIdx.x;
  int g = t >> 3, j = t & 7;
  int n = blockIdx.x * 32 + g;
  if (n >= NN) return;
  float4 sdv = ((const float4*)sdst)[n];
  float sda[4] = {sdv.x, sdv.y, sdv.z, sdv.w};
  int e0 = row_off[n], e1 = row_off[n + 1];
  float m[4], den[4];
  float4 acc[4];
#pragma unroll
  for (int h = 0; h < 4; h++) {
    m[h] = -1e30f;
    den[h] = 0.f;
    acc[h] = make_float4(0.f, 0.f, 0.f, 0.f);
  }
  for (int e = e0; e < e1; ++e) {
    int src = csr_src[e];
    ull pk = apl[e];
    float4 ssv = ((const float4*)ssrc)[src];
    float ssa[4] = {ssv.x, ssv.y, ssv.z, ssv.w};
    uint2 u = *(const uint2*)(h3b + (size_t)src * 32 + (j << 2));
    float hx0 = bf2f(u.x & 0xffffu), hx1 = bf2f(u.x >> 16);
    float hx2 = bf2f(u.y & 0xffffu), hx3 = bf2f(u.y >> 16);
#pragma unroll
    for (int h = 0; h < 4; h++) {
      float al = ssa[h] + sda[h] + bf2f((unsigned int)(unsigned short)(pk >> (16 * h)));
      al = lrelu(al, 0.2f);
      float nm = fmaxf(m[h], al);
      float c1 = __expf(m[h] - nm);
      float p = __expf(al - nm);
      den[h] = den[h] * c1 + p;
      acc[h].x = acc[h].x * c1 + p * hx0;
      acc[h].y = acc[h].y * c1 + p * hx1;
      acc[h].z = acc[h].z * c1 + p * hx2;
      acc[h].w = acc[h].w * c1 + p * hx3;
      m[h] = nm;
    }
  }
#pragma unroll
  for (int h = 0; h < 4; h++) {
    float inv = 1.f / (den[h] + 1e-16f);
    unsigned int u0 = (unsigned)f2bf(acc[h].x * inv) | ((unsigned)f2bf(acc[h].y * inv) << 16);
    unsigned int u1 = (unsigned)f2bf(acc[h].z * inv) | ((unsigned)f2bf(acc[h].w * inv) << 16);
    *(uint2*)(aggb + (size_t)n * 128 + h * 32 + (j << 2)) = make_uint2(u0, u1);
  }
}

// ---- layer-4 epilogue: [N,128](bf16) @ W4p[128,64] + b4, lrelu -> h4 ----
__global__ __launch_bounds__(256) void k_epi4(const unsigned short* __restrict__ aggb,
                                              const float* __restrict__ sm,
                                              const float* __restrict__ b4,
                                              float* __restrict__ h4) {
  __shared__ float4 sW[2048];
  __shared__ float sb[64];
  int t = threadIdx.x;
  for (int i = t; i < 2048; i += 256) sW[i] = ((const float4*)(sm + SM_W4P))[i];
  if (t < 64) sb[t] = b4[t];
  __syncthreads();
  int n = blockIdx.x * 256 + t;
  if (n >= NN) return;
  float acc[64];
#pragma unroll
  for (int j = 0; j < 64; j++) acc[j] = 0.f;
  const unsigned short* r = aggb + (size_t)n * 128;
  for (int k = 0; k < 128; k += 4) {
    uint2 u = *(const uint2*)(r + k);
    float va[4] = {bf2f(u.x & 0xffffu), bf2f(u.x >> 16), bf2f(u.y & 0xffffu),
                   bf2f(u.y >> 16)};
#pragma unroll
    for (int kk = 0; kk < 4; kk++) {
#pragma unroll
      for (int j4 = 0; j4 < 16; j4++) {
        float4 wv = sW[(k + kk) * 16 + j4];
        acc[j4 * 4 + 0] += va[kk] * wv.x;
        acc[j4 * 4 + 1] += va[kk] * wv.y;
        acc[j4 * 4 + 2] += va[kk] * wv.z;
        acc[j4 * 4 + 3] += va[kk] * wv.w;
      }
    }
  }
  float* o = h4 + (size_t)n * 64;
#pragma unroll
  for (int j4 = 0; j4 < 16; j4++) {
    float4 ov;
    ov.x = lrelu(acc[j4 * 4 + 0] + sb[j4 * 4 + 0], 0.01f);
    ov.y = lrelu(acc[j4 * 4 + 1] + sb[j4 * 4 + 1], 0.01f);
    ov.z = lrelu(acc[j4 * 4 + 2] + sb[j4 * 4 + 2], 0.01f);
    ov.w = lrelu(acc[j4 * 4 + 3] + sb[j4 * 4 + 3], 0.01f);
    ((float4*)o)[j4] = ov;
  }
}

// ---- pooling ----
__global__ __launch_bounds__(256) void k_pool1(const float* __restrict__ h4,
                                               const int* __restrict__ sidx,
                                               float* __restrict__ pool1) {
  int i = blockIdx.x * 256 + threadIdx.x;
  if (i >= NN * 64) return;
  int n = i >> 6, c = i & 63;
  atomicAdd(&pool1[(size_t)sidx[n] * 64 + c], h4[i]);
}

__global__ __launch_bounds__(256) void k_pool2(const float* __restrict__ pool1,
                                               const float* __restrict__ snorm,
                                               const int* __restrict__ nodes,
                                               float* __restrict__ pool2) {
  int i = blockIdx.x * 256 + threadIdx.x;
  if (i >= MM * 64) return;
  int mi = i >> 6, c = i & 63;
  float v = pool1[i] / snorm[mi];
  atomicAdd(&pool2[(size_t)nodes[mi] * 64 + c], v);
}

// ---- final head: one wave per group ----
__global__ __launch_bounds__(64) void k_final(const float* __restrict__ pool2,
                                              const float* __restrict__ h4,
                                              const int* __restrict__ dvi,
                                              const float* __restrict__ Wp,
                                              const float* __restrict__ Wt,
                                              const float* __restrict__ Wo,
                                              const float* __restrict__ bo,
                                              float* __restrict__ out) {
  __shared__ float p[64], tt[64];
  int gI = blockIdx.x, j = threadIdx.x;
  p[j] = pool2[gI * 64 + j];
  tt[j] = h4[(size_t)dvi[gI] * 64 + j];
  __syncthreads();
  float f1 = 0.f, f2 = 0.f;
#pragma unroll 8
  for (int c = 0; c < 64; c++) {
    f1 += p[c] * Wp[c * 64 + j];
    f2 += tt[c] * Wt[c * 64 + j];
  }
  f1 = lrelu(f1, 0.01f);
  f2 = lrelu(f2, 0.01f);
  float v = f1 * Wo[j] + f2 * Wo[64 + j];
  for (int off = 32; off > 0; off >>= 1) v += __shfl_down(v, off, 64);
  if (j == 0) out[gI] = v + bo[0];
}

extern "C" void kernel_launch(void* const* d_in, const int* in_sizes, int n_in,
                              void* d_out, int out_size, void* d_ws, size_t ws_size,
                              hipStream_t stream) {
  const float* x = (const float*)d_in[0];
  const int* ei = (const int*)d_in[1];
  const float* ea = (const float*)d_in[2];
  const int* sidx = (const int*)d_in[3];
  const float* snorm = (const float*)d_in[4];
  const int* nodes = (const int*)d_in[5];
  const int* dvi = (const int*)d_in[6];
  const float* W1 = (const float*)d_in[7];
  const float* as1 = (const float*)d_in[9];
  const float* ad1 = (const float*)d_in[10];
  const float* b1 = (const float*)d_in[12];
  const float* W2 = (const float*)d_in[13];
  const float* as2 = (const float*)d_in[15];
  const float* ad2 = (const float*)d_in[16];
  const float* b2 = (const float*)d_in[18];
  const float* W3 = (const float*)d_in[19];
  const float* as3 = (const float*)d_in[21];
  const float* ad3 = (const float*)d_in[22];
  const float* b3 = (const float*)d_in[24];
  const float* b4 = (const float*)d_in[30];
  const float* Wp = (const float*)d_in[31];
  const float* Wt = (const float*)d_in[32];
  const float* Wo = (const float*)d_in[33];
  const float* bo = (const float*)d_in[34];
  float* out = (float*)d_out;

  char* w = (char*)d_ws;
  size_t off = 0;
  auto take = [&](size_t bytes) -> char* {
    char* p = w + off;
    off = (off + bytes + 255) & ~(size_t)255;
    return p;
  };
  int* row_off = (int*)take((size_t)(NN + 1) * 4);
  float* sm = (float*)take(SM_TOTAL * 4);
  int2* pairs = (int2*)take((size_t)ETOT * 8);
  int* csr_src = (int*)take((size_t)ETOT * 4);
  ull* apc = (ull*)take((size_t)ETOT * 4 * 8);
  int* blk_cnt = (int*)take((size_t)NB1 * NBUCK * 4);
  int* blk_base_T = (int*)take((size_t)NBUCK * NB1 * 4);
  int* bucket_tot = (int*)take((size_t)NBUCK * 4);
  int* bucket_base = (int*)take((size_t)(NBUCK + 1) * 4);
  // overlay: aepack4 (dead after k_sort2) shares space with h4 + aggb
  char* region = take((size_t)EE * 4 * 8);  // 51.2 MB
  ull* aepack4 = (ull*)region;
  float* h4 = (float*)region;
  unsigned short* aggb = (unsigned short*)(region + (size_t)NN * 64 * 4);
  unsigned short* hxb = (unsigned short*)take((size_t)NN * 32 * 2);
  unsigned short* h3b = (unsigned short*)take((size_t)NN * 32 * 2);
  float* ssrc = (float*)take((size_t)NN * 4 * 4);
  float* sdst = (float*)take((size_t)NN * 4 * 4);
  float* bufA = (float*)take((size_t)NN * 32 * 4);
  float* bufB = (float*)take((size_t)NN * 32 * 4);
  float* pool1 = (float*)take((size_t)MM * 64 * 4);
  float* pool2 = (float*)take((size_t)GG * 64 * 4);
  if (off > ws_size) return;  // workspace too small -> visible validation failure

  hipMemsetAsync(sm, 0, 64, stream);
  hipMemsetAsync(pool1, 0, (size_t)MM * 64 * 4, stream);
  hipMemsetAsync(pool2, 0, (size_t)GG * 64 * 4, stream);

  k_pre<<<1, 256, 0, stream>>>(sm, (const float*)d_in[8], (const float*)d_in[14],
                               (const float*)d_in[20], (const float*)d_in[26],
                               (const float*)d_in[11], (const float*)d_in[17],
                               (const float*)d_in[23], (const float*)d_in[29],
                               (const float*)d_in[27], (const float*)d_in[28],
                               (const float*)d_in[25]);
  k_aecomp<<<2048, 256, 0, stream>>>(ea, sm, aepack4);
  k_selfpack<<<1, 64, 0, stream>>>(sm);

  // counting sort by dst (two-level, no global atomics)
  k_hist1<<<NB1, 1024, 0, stream>>>(ei, blk_cnt);
  k_bscan_a<<<NBUCK, 256, 0, stream>>>(blk_cnt, blk_base_T, bucket_tot);
  k_bscan_b<<<1, 1024, 0, stream>>>(bucket_tot, bucket_base, row_off);
  k_scatter1<<<NB1, 1024, 0, stream>>>(ei, bucket_base, blk_base_T, pairs);
  k_sort2<<<NBUCK, 256, 0, stream>>>(pairs, bucket_base, ei, aepack4, sm, row_off,
                                     csr_src, apc);

  // layer 1
  k_t<64><<<NB_N256, 256, 0, stream>>>(x, W1, as1, ad1, hxb, ssrc, sdst);
  k_agg<<<NB_AGG, 256, 0, stream>>>(row_off, csr_src, apc, hxb, ssrc, sdst, b1, bufA);
  // layer 2
  k_t<32><<<NB_N256, 256, 0, stream>>>(bufA, W2, as2, ad2, hxb, ssrc, sdst);
  k_agg<<<NB_AGG, 256, 0, stream>>>(row_off, csr_src, apc + (size_t)ETOT, hxb, ssrc,
                                    sdst, b2, bufB);
  // layer 3
  k_t<32><<<NB_N256, 256, 0, stream>>>(bufB, W3, as3, ad3, hxb, ssrc, sdst);
  k_agg<<<NB_AGG, 256, 0, stream>>>(row_off, csr_src, apc + 2 * (size_t)ETOT, hxb, ssrc,
                                    sdst, b3, bufA);
  // layer 4
  k_t4<<<NB_N256, 256, 0, stream>>>(bufA, sm, h3b, ssrc, sdst);
  k_agg4<<<NB_AGG, 256, 0, stream>>>(row_off, csr_src, apc + 3 * (size_t)ETOT, h3b, ssrc,
                                     sdst, aggb);
  k_epi4<<<NB_N256, 256, 0, stream>>>(aggb, sm, b4, h4);

  // pooling head
  k_pool1<<<(NN * 64) / 256, 256, 0, stream>>>(h4, sidx, pool1);
  k_pool2<<<(MM * 64) / 256, 256, 0, stream>>>(pool1, snorm, nodes, pool2);
  k_final<<<GG, 64, 0, stream>>>(pool2, h4, dvi, Wp, Wt, Wo, bo, out);
}

// Round 4
// 728.028 us; speedup vs baseline: 1.3242x; 1.1439x over previous
//
#include <hip/hip_runtime.h>
#include <math.h>

#define NN 100000
#define EE 1600000
#define ETOT 1700000
#define MM 20000
#define GG 512

#define NBUCK 782   // ceil(100000/128)
#define NB1 256     // phase-1 blocks (must match k_bscan_a's 256 threads)
#define CAP 4096    // max edges per bucket held in LDS (expected 2174 +- 47)

static constexpr int NB_N256 = (NN + 255) / 256;    // 391
static constexpr int NB_AGG  = NN / 32;             // 3125

// small-buffer layout (float indices)
#define SM_MEAN 0
#define SM_WEA 16
#define SM_VS4 272
#define SM_VD4 400
#define SM_W4P 536
#define SM_TOTAL 8728

typedef unsigned long long ull;

__device__ __forceinline__ unsigned short f2bf(float f) {
  unsigned int u = __float_as_uint(f);
  u += 0x7fffu + ((u >> 16) & 1u);
  return (unsigned short)(u >> 16);
}
__device__ __forceinline__ float bf2f(unsigned int h) {
  return __uint_as_float(h << 16);
}
__device__ __forceinline__ float lrelu(float v, float s) { return v > 0.f ? v : s * v; }

// ---- precompute reduced weights ----
__global__ __launch_bounds__(256) void k_pre(
    float* __restrict__ sm, const float* __restrict__ We1, const float* __restrict__ We2,
    const float* __restrict__ We3, const float* __restrict__ We4,
    const float* __restrict__ ae1, const float* __restrict__ ae2,
    const float* __restrict__ ae3, const float* __restrict__ ae4,
    const float* __restrict__ as4, const float* __restrict__ ad4,
    const float* __restrict__ W4) {
  int t = threadIdx.x;
  {
    int l = t >> 6, d = (t >> 2) & 15, h = t & 3;
    const float* We = (l == 0) ? We1 : (l == 1) ? We2 : (l == 2) ? We3 : We4;
    const float* ae = (l == 0) ? ae1 : (l == 1) ? ae2 : (l == 2) ? ae3 : ae4;
    int C = (l == 3) ? 64 : 8;
    float s = 0.f;
    for (int c = 0; c < C; c++) s += We[d * (4 * C) + h * C + c] * ae[h * C + c];
    sm[SM_WEA + l * 64 + d * 4 + h] = s;
  }
  if (t < 128) {
    int k = t >> 2, h = t & 3;
    float s1 = 0.f, s2 = 0.f;
    for (int c = 0; c < 64; c++) {
      float w = W4[k * 256 + h * 64 + c];
      s1 += w * as4[h * 64 + c];
      s2 += w * ad4[h * 64 + c];
    }
    sm[SM_VS4 + t] = s1;
    sm[SM_VD4 + t] = s2;
  }
  for (int i = t; i < 8192; i += 256) {
    int row = i >> 6, c = i & 63;
    int h = row >> 5, k = row & 31;
    sm[SM_W4P + i] = 0.25f * W4[k * 256 + h * 64 + c];
  }
}

// ---- sort phase 1: per-block bucket histogram + fused ea dim-sum reduction ----
__global__ __launch_bounds__(1024) void k_hist1(const int* __restrict__ ei,
                                                const float* __restrict__ ea,
                                                int* __restrict__ blk_cnt,
                                                float* __restrict__ sm) {
  __shared__ int hist[NBUCK];
  __shared__ float lsum[16];
  int t = threadIdx.x;
  for (int i = t; i < NBUCK; i += 1024) hist[i] = 0;
  if (t < 16) lsum[t] = 0.f;
  __syncthreads();
  for (int e = blockIdx.x * 1024 + t; e < ETOT; e += NB1 * 1024) {
    int dst = (e < EE) ? ei[EE + e] : (e - EE);
    atomicAdd(&hist[dst >> 7], 1);
  }
  // fused ea column-sum: stride NB1*1024 is a multiple of 4, so (i&3) is fixed/thread
  {
    const float4* ea4 = (const float4*)ea;
    int q = t & 3;
    float4 a = make_float4(0.f, 0.f, 0.f, 0.f);
    for (size_t i = (size_t)blockIdx.x * 1024 + t; i < (size_t)EE * 4;
         i += (size_t)NB1 * 1024) {
      float4 v = ea4[i];
      a.x += v.x; a.y += v.y; a.z += v.z; a.w += v.w;
    }
    // reduce across lanes with equal (lane&3)
    for (int m = 4; m < 64; m <<= 1) {
      a.x += __shfl_xor(a.x, m, 64);
      a.y += __shfl_xor(a.y, m, 64);
      a.z += __shfl_xor(a.z, m, 64);
      a.w += __shfl_xor(a.w, m, 64);
    }
    if ((t & 63) < 4) {
      atomicAdd(&lsum[q * 4 + 0], a.x);
      atomicAdd(&lsum[q * 4 + 1], a.y);
      atomicAdd(&lsum[q * 4 + 2], a.z);
      atomicAdd(&lsum[q * 4 + 3], a.w);
    }
  }
  __syncthreads();
  for (int i = t; i < NBUCK; i += 1024) blk_cnt[blockIdx.x * NBUCK + i] = hist[i];
  if (t < 16) atomicAdd(&sm[SM_MEAN + t], lsum[t]);
}

// ---- scan A: per-bucket exclusive scan over the 256 blocks ----
__global__ __launch_bounds__(256) void k_bscan_a(const int* __restrict__ blk_cnt,
                                                 int* __restrict__ blk_base_T,
                                                 int* __restrict__ bucket_tot) {
  __shared__ int s[256];
  int b = blockIdx.x, t = threadIdx.x;
  int v = blk_cnt[t * NBUCK + b];
  s[t] = v;
  __syncthreads();
  for (int off = 1; off < 256; off <<= 1) {
    int x = (t >= off) ? s[t - off] : 0;
    __syncthreads();
    s[t] += x;
    __syncthreads();
  }
  blk_base_T[b * 256 + t] = s[t] - v;
  if (t == 255) bucket_tot[b] = s[255];
}

// ---- scan B: exclusive scan of bucket totals ----
__global__ __launch_bounds__(1024) void k_bscan_b(const int* __restrict__ bucket_tot,
                                                  int* __restrict__ bucket_base,
                                                  int* __restrict__ row_off) {
  __shared__ int s[1024];
  int t = threadIdx.x;
  int v = (t < NBUCK) ? bucket_tot[t] : 0;
  s[t] = v;
  __syncthreads();
  for (int off = 1; off < 1024; off <<= 1) {
    int x = (t >= off) ? s[t - off] : 0;
    __syncthreads();
    s[t] += x;
    __syncthreads();
  }
  if (t < NBUCK) bucket_base[t] = s[t] - v;
  if (t == 0) {
    bucket_base[NBUCK] = ETOT;
    row_off[NN] = ETOT;
  }
}

// ---- sort phase 1 scatter: packed (src, eid|dstlow) into dense bucket regions ----
__global__ __launch_bounds__(1024) void k_scatter1(const int* __restrict__ ei,
                                                   const int* __restrict__ bucket_base,
                                                   const int* __restrict__ blk_base_T,
                                                   uint2* __restrict__ pairs) {
  __shared__ int base[NBUCK];
  __shared__ int rank[NBUCK];
  int t = threadIdx.x, blk = blockIdx.x;
  for (int i = t; i < NBUCK; i += 1024) {
    base[i] = bucket_base[i] + blk_base_T[i * 256 + blk];
    rank[i] = 0;
  }
  __syncthreads();
  for (int e = blk * 1024 + t; e < ETOT; e += NB1 * 1024) {
    int src, dst;
    if (e < EE) {
      src = ei[e];
      dst = ei[EE + e];
    } else {
      src = dst = e - EE;
    }
    int bin = dst >> 7;
    int r = atomicAdd(&rank[bin], 1);
    pairs[base[bin] + r] =
        make_uint2((unsigned)src, (unsigned)e | ((unsigned)(dst & 127) << 21));
  }
}

// ---- sort phase 2: LDS exact sort + fused CSR-order pack GEMV, coalesced writes ----
__global__ __launch_bounds__(256) void k_sort2(const uint2* __restrict__ pairs,
                                               const int* __restrict__ bucket_base,
                                               const float* __restrict__ ea,
                                               const float* __restrict__ sm,
                                               int* __restrict__ row_off,
                                               int* __restrict__ csr_src,
                                               ull* __restrict__ apc) {
  __shared__ uint2 plds[CAP];
  __shared__ unsigned short perm[CAP];
  __shared__ int hist[128];
  __shared__ int scan[128];
  __shared__ int rankv[128];
  __shared__ float sWea[256];
  __shared__ float smean[16];
  int b = blockIdx.x, t = threadIdx.x;
  int start = bucket_base[b], end = bucket_base[b + 1];
  int cnt = end - start;
  sWea[t] = sm[SM_WEA + t];
  if (t < 16) smean[t] = sm[SM_MEAN + t] * (1.f / EE);
  if (t < 128) hist[t] = 0;
  __syncthreads();
  bool fits = (cnt <= CAP);
  if (fits) {
    for (int i = t; i < cnt; i += 256) {
      uint2 pe = pairs[start + i];
      plds[i] = pe;
      atomicAdd(&hist[(pe.y >> 21) & 127], 1);
    }
  } else {
    for (int i = t; i < cnt; i += 256)
      atomicAdd(&hist[(pairs[start + i].y >> 21) & 127], 1);
  }
  __syncthreads();
  if (t < 128) scan[t] = hist[t];
  __syncthreads();
  for (int off = 1; off < 128; off <<= 1) {
    int x = (t >= off && t < 128) ? scan[t - off] : 0;
    __syncthreads();
    if (t < 128) scan[t] += x;
    __syncthreads();
  }
  if (t < 128) {
    int excl = scan[t] - hist[t];
    rankv[t] = excl;
    int dst = b * 128 + t;
    if (dst < NN) row_off[dst] = start + excl;
  }
  __syncthreads();
  if (fits) {
    // build in-bucket permutation, then emit in rank order (coalesced writes)
    for (int i = t; i < cnt; i += 256) {
      int bin = (plds[i].y >> 21) & 127;
      int r = atomicAdd(&rankv[bin], 1);
      perm[r] = (unsigned short)i;
    }
    __syncthreads();
    for (int r = t; r < cnt; r += 256) {
      uint2 pe = plds[perm[r]];
      unsigned eid = pe.y & 0x1fffffu;
      int pos = start + r;
      csr_src[pos] = (int)pe.x;
      float eav[16];
      if (eid < EE) {
        const float4* p = (const float4*)(ea + (size_t)eid * 16);
        float4 v0 = p[0], v1 = p[1], v2 = p[2], v3 = p[3];
        eav[0] = v0.x; eav[1] = v0.y; eav[2] = v0.z; eav[3] = v0.w;
        eav[4] = v1.x; eav[5] = v1.y; eav[6] = v1.z; eav[7] = v1.w;
        eav[8] = v2.x; eav[9] = v2.y; eav[10] = v2.z; eav[11] = v2.w;
        eav[12] = v3.x; eav[13] = v3.y; eav[14] = v3.z; eav[15] = v3.w;
      } else {
#pragma unroll
        for (int d = 0; d < 16; d++) eav[d] = smean[d];
      }
#pragma unroll
      for (int l = 0; l < 4; l++) {
        ull pk = 0;
#pragma unroll
        for (int h = 0; h < 4; h++) {
          float s = 0.f;
#pragma unroll
          for (int d = 0; d < 16; d++) s += eav[d] * sWea[l * 64 + d * 4 + h];
          pk |= (ull)f2bf(s) << (16 * h);
        }
        apc[(size_t)l * ETOT + pos] = pk;
      }
    }
  } else {
    // overflow fallback (never taken for this dataset): scattered writes
    for (int i = t; i < cnt; i += 256) {
      uint2 pe = pairs[start + i];
      int bin = (pe.y >> 21) & 127;
      unsigned eid = pe.y & 0x1fffffu;
      int r = atomicAdd(&rankv[bin], 1);
      int pos = start + r;
      csr_src[pos] = (int)pe.x;
      float eav[16];
      if (eid < EE) {
        const float4* p = (const float4*)(ea + (size_t)eid * 16);
        float4 v0 = p[0], v1 = p[1], v2 = p[2], v3 = p[3];
        eav[0] = v0.x; eav[1] = v0.y; eav[2] = v0.z; eav[3] = v0.w;
        eav[4] = v1.x; eav[5] = v1.y; eav[6] = v1.z; eav[7] = v1.w;
        eav[8] = v2.x; eav[9] = v2.y; eav[10] = v2.z; eav[11] = v2.w;
        eav[12] = v3.x; eav[13] = v3.y; eav[14] = v3.z; eav[15] = v3.w;
      } else {
#pragma unroll
        for (int d = 0; d < 16; d++) eav[d] = smean[d];
      }
#pragma unroll
      for (int l = 0; l < 4; l++) {
        ull pk = 0;
#pragma unroll
        for (int h = 0; h < 4; h++) {
          float s = 0.f;
#pragma unroll
          for (int d = 0; d < 16; d++) s += eav[d] * sWea[l * 64 + d * 4 + h];
          pk |= (ull)f2bf(s) << (16 * h);
        }
        apc[(size_t)l * ETOT + pos] = pk;
      }
    }
  }
}

// ---- node transform: hx = in@W (bf16 out), alpha_src/dst reductions ----
template <int DIN>
__global__ __launch_bounds__(256) void k_t(const float* __restrict__ in,
                                           const float* __restrict__ W,
                                           const float* __restrict__ a_s,
                                           const float* __restrict__ a_d,
                                           unsigned short* __restrict__ hxb,
                                           float* __restrict__ ssrc,
                                           float* __restrict__ sdst) {
  __shared__ float4 sW[DIN * 8];
  __shared__ float sas[32], sad[32];
  int t = threadIdx.x;
  for (int i = t; i < DIN * 8; i += 256) sW[i] = ((const float4*)W)[i];
  if (t < 32) { sas[t] = a_s[t]; sad[t] = a_d[t]; }
  __syncthreads();
  int n = blockIdx.x * 256 + t;
  if (n >= NN) return;
  float acc[32];
#pragma unroll
  for (int j = 0; j < 32; j++) acc[j] = 0.f;
  const float* xr = in + (size_t)n * DIN;
  for (int k = 0; k < DIN; k += 4) {
    float4 xv = *(const float4*)(xr + k);
    float xa[4] = {xv.x, xv.y, xv.z, xv.w};
#pragma unroll
    for (int kk = 0; kk < 4; kk++) {
#pragma unroll
      for (int j4 = 0; j4 < 8; j4++) {
        float4 ww = sW[(k + kk) * 8 + j4];
        acc[j4 * 4 + 0] += xa[kk] * ww.x;
        acc[j4 * 4 + 1] += xa[kk] * ww.y;
        acc[j4 * 4 + 2] += xa[kk] * ww.z;
        acc[j4 * 4 + 3] += xa[kk] * ww.w;
      }
    }
  }
  float ssum[4], dsum[4];
#pragma unroll
  for (int h = 0; h < 4; h++) {
    float s = 0.f, d = 0.f;
#pragma unroll
    for (int c = 0; c < 8; c++) {
      s += acc[h * 8 + c] * sas[h * 8 + c];
      d += acc[h * 8 + c] * sad[h * 8 + c];
    }
    ssum[h] = s;
    dsum[h] = d;
  }
  unsigned int up[16];
#pragma unroll
  for (int i = 0; i < 16; i++)
    up[i] = (unsigned)f2bf(acc[2 * i]) | ((unsigned)f2bf(acc[2 * i + 1]) << 16);
  uint4* ho = (uint4*)(hxb + (size_t)n * 32);
  ho[0] = make_uint4(up[0], up[1], up[2], up[3]);
  ho[1] = make_uint4(up[4], up[5], up[6], up[7]);
  ho[2] = make_uint4(up[8], up[9], up[10], up[11]);
  ho[3] = make_uint4(up[12], up[13], up[14], up[15]);
  ((float4*)ssrc)[n] = make_float4(ssum[0], ssum[1], ssum[2], ssum[3]);
  ((float4*)sdst)[n] = make_float4(dsum[0], dsum[1], dsum[2], dsum[3]);
}

// ---- layer-4 attention reductions + bf16 copy of h3 ----
__global__ __launch_bounds__(256) void k_t4(const float* __restrict__ h3,
                                            const float* __restrict__ sm,
                                            unsigned short* __restrict__ h3b,
                                            float* __restrict__ ssrc,
                                            float* __restrict__ sdst) {
  __shared__ float sVs[128], sVd[128];
  int t = threadIdx.x;
  if (t < 128) { sVs[t] = sm[SM_VS4 + t]; sVd[t] = sm[SM_VD4 + t]; }
  __syncthreads();
  int n = blockIdx.x * 256 + t;
  if (n >= NN) return;
  const float* r = h3 + (size_t)n * 32;
  float v[32];
#pragma unroll
  for (int k = 0; k < 32; k++) v[k] = r[k];
  float s0 = 0, s1 = 0, s2 = 0, s3 = 0, d0 = 0, d1 = 0, d2 = 0, d3 = 0;
#pragma unroll
  for (int k = 0; k < 32; k++) {
    s0 += v[k] * sVs[k * 4 + 0]; s1 += v[k] * sVs[k * 4 + 1];
    s2 += v[k] * sVs[k * 4 + 2]; s3 += v[k] * sVs[k * 4 + 3];
    d0 += v[k] * sVd[k * 4 + 0]; d1 += v[k] * sVd[k * 4 + 1];
    d2 += v[k] * sVd[k * 4 + 2]; d3 += v[k] * sVd[k * 4 + 3];
  }
  unsigned int up[16];
#pragma unroll
  for (int i = 0; i < 16; i++)
    up[i] = (unsigned)f2bf(v[2 * i]) | ((unsigned)f2bf(v[2 * i + 1]) << 16);
  uint4* ho = (uint4*)(h3b + (size_t)n * 32);
  ho[0] = make_uint4(up[0], up[1], up[2], up[3]);
  ho[1] = make_uint4(up[4], up[5], up[6], up[7]);
  ho[2] = make_uint4(up[8], up[9], up[10], up[11]);
  ho[3] = make_uint4(up[12], up[13], up[14], up[15]);
  ((float4*)ssrc)[n] = make_float4(s0, s1, s2, s3);
  ((float4*)sdst)[n] = make_float4(d0, d1, d2, d3);
}

// ---- layers 1-3 aggregation: 8 lanes/node, online softmax, fused epilogue ----
__global__ __launch_bounds__(256) void k_agg(const int* __restrict__ row_off,
                                             const int* __restrict__ csr_src,
                                             const ull* __restrict__ apl,
                                             const unsigned short* __restrict__ hxb,
                                             const float* __restrict__ ssrc,
                                             const float* __restrict__ sdst,
                                             const float* __restrict__ bias,
                                             float* __restrict__ outp) {
  int t = threadIdx.x;
  int g = t >> 3, j = t & 7, h = j >> 1;
  int n = blockIdx.x * 32 + g;
  if (n >= NN) return;
  float sd = sdst[n * 4 + h];
  int e0 = row_off[n], e1 = row_off[n + 1];
  float m = -1e30f, den = 0.f;
  float4 acc = make_float4(0.f, 0.f, 0.f, 0.f);
  for (int e = e0; e < e1; ++e) {
    int src = csr_src[e];
    ull pk = apl[e];
    float ae = bf2f((unsigned int)(unsigned short)(pk >> (16 * h)));
    float al = ssrc[src * 4 + h] + sd + ae;
    al = lrelu(al, 0.2f);
    uint2 u = *(const uint2*)(hxb + (size_t)src * 32 + (j << 2));
    float nm = fmaxf(m, al);
    float c1 = __expf(m - nm);
    float p = __expf(al - nm);
    den = den * c1 + p;
    acc.x = acc.x * c1 + p * bf2f(u.x & 0xffffu);
    acc.y = acc.y * c1 + p * bf2f(u.x >> 16);
    acc.z = acc.z * c1 + p * bf2f(u.y & 0xffffu);
    acc.w = acc.w * c1 + p * bf2f(u.y >> 16);
    m = nm;
  }
  float inv = 1.f / (den + 1e-16f);
  float4 b = *(const float4*)(bias + (j << 2));
  float4 o;
  o.x = lrelu(acc.x * inv + b.x, 0.01f);
  o.y = lrelu(acc.y * inv + b.y, 0.01f);
  o.z = lrelu(acc.z * inv + b.z, 0.01f);
  o.w = lrelu(acc.w * inv + b.w, 0.01f);
  *(float4*)(outp + (size_t)n * 32 + (j << 2)) = o;
}

// ---- layer-4 aggregation: aggregate h3 per head, bf16 out ----
__global__ __launch_bounds__(256) void k_agg4(const int* __restrict__ row_off,
                                              const int* __restrict__ csr_src,
                                              const ull* __restrict__ apl,
                                              const unsigned short* __restrict__ h3b,
                                              const float* __restrict__ ssrc,
                                              const float* __restrict__ sdst,
                                              unsigned short* __restrict__ aggb) {
  int t = threadIdx.x;
  int g = t >> 3, j = t & 7;
  int n = blockIdx.x * 32 + g;
  if (n >= NN) return;
  float4 sdv = ((const float4*)sdst)[n];
  float sda[4] = {sdv.x, sdv.y, sdv.z, sdv.w};
  int e0 = row_off[n], e1 = row_off[n + 1];
  float m[4], den[4];
  float4 acc[4];
#pragma unroll
  for (int h = 0; h < 4; h++) {
    m[h] = -1e30f;
    den[h] = 0.f;
    acc[h] = make_float4(0.f, 0.f, 0.f, 0.f);
  }
  for (int e = e0; e < e1; ++e) {
    int src = csr_src[e];
    ull pk = apl[e];
    float4 ssv = ((const float4*)ssrc)[src];
    float ssa[4] = {ssv.x, ssv.y, ssv.z, ssv.w};
    uint2 u = *(const uint2*)(h3b + (size_t)src * 32 + (j << 2));
    float hx0 = bf2f(u.x & 0xffffu), hx1 = bf2f(u.x >> 16);
    float hx2 = bf2f(u.y & 0xffffu), hx3 = bf2f(u.y >> 16);
#pragma unroll
    for (int h = 0; h < 4; h++) {
      float al = ssa[h] + sda[h] + bf2f((unsigned int)(unsigned short)(pk >> (16 * h)));
      al = lrelu(al, 0.2f);
      float nm = fmaxf(m[h], al);
      float c1 = __expf(m[h] - nm);
      float p = __expf(al - nm);
      den[h] = den[h] * c1 + p;
      acc[h].x = acc[h].x * c1 + p * hx0;
      acc[h].y = acc[h].y * c1 + p * hx1;
      acc[h].z = acc[h].z * c1 + p * hx2;
      acc[h].w = acc[h].w * c1 + p * hx3;
      m[h] = nm;
    }
  }
#pragma unroll
  for (int h = 0; h < 4; h++) {
    float inv = 1.f / (den[h] + 1e-16f);
    unsigned int u0 = (unsigned)f2bf(acc[h].x * inv) | ((unsigned)f2bf(acc[h].y * inv) << 16);
    unsigned int u1 = (unsigned)f2bf(acc[h].z * inv) | ((unsigned)f2bf(acc[h].w * inv) << 16);
    *(uint2*)(aggb + (size_t)n * 128 + h * 32 + (j << 2)) = make_uint2(u0, u1);
  }
}

// ---- layer-4 epilogue: [N,128](bf16) @ W4p[128,64] + b4, lrelu -> h4 ----
__global__ __launch_bounds__(256) void k_epi4(const unsigned short* __restrict__ aggb,
                                              const float* __restrict__ sm,
                                              const float* __restrict__ b4,
                                              float* __restrict__ h4) {
  __shared__ float4 sW[2048];
  __shared__ float sb[64];
  int t = threadIdx.x;
  for (int i = t; i < 2048; i += 256) sW[i] = ((const float4*)(sm + SM_W4P))[i];
  if (t < 64) sb[t] = b4[t];
  __syncthreads();
  int n = blockIdx.x * 256 + t;
  if (n >= NN) return;
  float acc[64];
#pragma unroll
  for (int j = 0; j < 64; j++) acc[j] = 0.f;
  const unsigned short* r = aggb + (size_t)n * 128;
  for (int k = 0; k < 128; k += 4) {
    uint2 u = *(const uint2*)(r + k);
    float va[4] = {bf2f(u.x & 0xffffu), bf2f(u.x >> 16), bf2f(u.y & 0xffffu),
                   bf2f(u.y >> 16)};
#pragma unroll
    for (int kk = 0; kk < 4; kk++) {
#pragma unroll
      for (int j4 = 0; j4 < 16; j4++) {
        float4 wv = sW[(k + kk) * 16 + j4];
        acc[j4 * 4 + 0] += va[kk] * wv.x;
        acc[j4 * 4 + 1] += va[kk] * wv.y;
        acc[j4 * 4 + 2] += va[kk] * wv.z;
        acc[j4 * 4 + 3] += va[kk] * wv.w;
      }
    }
  }
  float* o = h4 + (size_t)n * 64;
#pragma unroll
  for (int j4 = 0; j4 < 16; j4++) {
    float4 ov;
    ov.x = lrelu(acc[j4 * 4 + 0] + sb[j4 * 4 + 0], 0.01f);
    ov.y = lrelu(acc[j4 * 4 + 1] + sb[j4 * 4 + 1], 0.01f);
    ov.z = lrelu(acc[j4 * 4 + 2] + sb[j4 * 4 + 2], 0.01f);
    ov.w = lrelu(acc[j4 * 4 + 3] + sb[j4 * 4 + 3], 0.01f);
    ((float4*)o)[j4] = ov;
  }
}

// ---- pooling ----
__global__ __launch_bounds__(256) void k_pool1(const float* __restrict__ h4,
                                               const int* __restrict__ sidx,
                                               float* __restrict__ pool1) {
  int i = blockIdx.x * 256 + threadIdx.x;
  if (i >= NN * 64) return;
  int n = i >> 6, c = i & 63;
  atomicAdd(&pool1[(size_t)sidx[n] * 64 + c], h4[i]);
}

__global__ __launch_bounds__(256) void k_pool2(const float* __restrict__ pool1,
                                               const float* __restrict__ snorm,
                                               const int* __restrict__ nodes,
                                               float* __restrict__ pool2) {
  int i = blockIdx.x * 256 + threadIdx.x;
  if (i >= MM * 64) return;
  int mi = i >> 6, c = i & 63;
  float v = pool1[i] / snorm[mi];
  atomicAdd(&pool2[(size_t)nodes[mi] * 64 + c], v);
}

// ---- final head: one wave per group ----
__global__ __launch_bounds__(64) void k_final(const float* __restrict__ pool2,
                                              const float* __restrict__ h4,
                                              const int* __restrict__ dvi,
                                              const float* __restrict__ Wp,
                                              const float* __restrict__ Wt,
                                              const float* __restrict__ Wo,
                                              const float* __restrict__ bo,
                                              float* __restrict__ out) {
  __shared__ float p[64], tt[64];
  int gI = blockIdx.x, j = threadIdx.x;
  p[j] = pool2[gI * 64 + j];
  tt[j] = h4[(size_t)dvi[gI] * 64 + j];
  __syncthreads();
  float f1 = 0.f, f2 = 0.f;
#pragma unroll 8
  for (int c = 0; c < 64; c++) {
    f1 += p[c] * Wp[c * 64 + j];
    f2 += tt[c] * Wt[c * 64 + j];
  }
  f1 = lrelu(f1, 0.01f);
  f2 = lrelu(f2, 0.01f);
  float v = f1 * Wo[j] + f2 * Wo[64 + j];
  for (int off = 32; off > 0; off >>= 1) v += __shfl_down(v, off, 64);
  if (j == 0) out[gI] = v + bo[0];
}

extern "C" void kernel_launch(void* const* d_in, const int* in_sizes, int n_in,
                              void* d_out, int out_size, void* d_ws, size_t ws_size,
                              hipStream_t stream) {
  const float* x = (const float*)d_in[0];
  const int* ei = (const int*)d_in[1];
  const float* ea = (const float*)d_in[2];
  const int* sidx = (const int*)d_in[3];
  const float* snorm = (const float*)d_in[4];
  const int* nodes = (const int*)d_in[5];
  const int* dvi = (const int*)d_in[6];
  const float* W1 = (const float*)d_in[7];
  const float* as1 = (const float*)d_in[9];
  const float* ad1 = (const float*)d_in[10];
  const float* b1 = (const float*)d_in[12];
  const float* W2 = (const float*)d_in[13];
  const float* as2 = (const float*)d_in[15];
  const float* ad2 = (const float*)d_in[16];
  const float* b2 = (const float*)d_in[18];
  const float* W3 = (const float*)d_in[19];
  const float* as3 = (const float*)d_in[21];
  const float* ad3 = (const float*)d_in[22];
  const float* b3 = (const float*)d_in[24];
  const float* b4 = (const float*)d_in[30];
  const float* Wp = (const float*)d_in[31];
  const float* Wt = (const float*)d_in[32];
  const float* Wo = (const float*)d_in[33];
  const float* bo = (const float*)d_in[34];
  float* out = (float*)d_out;

  char* w = (char*)d_ws;
  size_t off = 0;
  auto take = [&](size_t bytes) -> char* {
    char* p = w + off;
    off = (off + bytes + 255) & ~(size_t)255;
    return p;
  };
  int* row_off = (int*)take((size_t)(NN + 1) * 4);
  float* sm = (float*)take(SM_TOTAL * 4);
  uint2* pairs = (uint2*)take((size_t)ETOT * 8);
  int* csr_src = (int*)take((size_t)ETOT * 4);
  ull* apc = (ull*)take((size_t)ETOT * 4 * 8);
  int* blk_cnt = (int*)take((size_t)NB1 * NBUCK * 4);
  int* blk_base_T = (int*)take((size_t)NBUCK * NB1 * 4);
  int* bucket_tot = (int*)take((size_t)NBUCK * 4);
  int* bucket_base = (int*)take((size_t)(NBUCK + 1) * 4);
  float* h4 = (float*)take((size_t)NN * 64 * 4);
  unsigned short* aggb = (unsigned short*)take((size_t)NN * 128 * 2);
  unsigned short* hxb = (unsigned short*)take((size_t)NN * 32 * 2);
  unsigned short* h3b = (unsigned short*)take((size_t)NN * 32 * 2);
  float* ssrc = (float*)take((size_t)NN * 4 * 4);
  float* sdst = (float*)take((size_t)NN * 4 * 4);
  float* bufA = (float*)take((size_t)NN * 32 * 4);
  float* bufB = (float*)take((size_t)NN * 32 * 4);
  float* pool1 = (float*)take((size_t)MM * 64 * 4);
  float* pool2 = (float*)take((size_t)GG * 64 * 4);
  if (off > ws_size) return;  // workspace too small -> visible validation failure

  hipMemsetAsync(sm, 0, 64, stream);
  hipMemsetAsync(pool1, 0, (size_t)MM * 64 * 4, stream);
  hipMemsetAsync(pool2, 0, (size_t)GG * 64 * 4, stream);

  k_pre<<<1, 256, 0, stream>>>(sm, (const float*)d_in[8], (const float*)d_in[14],
                               (const float*)d_in[20], (const float*)d_in[26],
                               (const float*)d_in[11], (const float*)d_in[17],
                               (const float*)d_in[23], (const float*)d_in[29],
                               (const float*)d_in[27], (const float*)d_in[28],
                               (const float*)d_in[25]);

  // counting sort by dst (two-level, no global atomics); ea-mean fused in hist1
  k_hist1<<<NB1, 1024, 0, stream>>>(ei, ea, blk_cnt, sm);
  k_bscan_a<<<NBUCK, 256, 0, stream>>>(blk_cnt, blk_base_T, bucket_tot);
  k_bscan_b<<<1, 1024, 0, stream>>>(bucket_tot, bucket_base, row_off);
  k_scatter1<<<NB1, 1024, 0, stream>>>(ei, bucket_base, blk_base_T, pairs);
  k_sort2<<<NBUCK, 256, 0, stream>>>(pairs, bucket_base, ea, sm, row_off, csr_src, apc);

  // layer 1
  k_t<64><<<NB_N256, 256, 0, stream>>>(x, W1, as1, ad1, hxb, ssrc, sdst);
  k_agg<<<NB_AGG, 256, 0, stream>>>(row_off, csr_src, apc, hxb, ssrc, sdst, b1, bufA);
  // layer 2
  k_t<32><<<NB_N256, 256, 0, stream>>>(bufA, W2, as2, ad2, hxb, ssrc, sdst);
  k_agg<<<NB_AGG, 256, 0, stream>>>(row_off, csr_src, apc + (size_t)ETOT, hxb, ssrc,
                                    sdst, b2, bufB);
  // layer 3
  k_t<32><<<NB_N256, 256, 0, stream>>>(bufB, W3, as3, ad3, hxb, ssrc, sdst);
  k_agg<<<NB_AGG, 256, 0, stream>>>(row_off, csr_src, apc + 2 * (size_t)ETOT, hxb, ssrc,
                                    sdst, b3, bufA);
  // layer 4
  k_t4<<<NB_N256, 256, 0, stream>>>(bufA, sm, h3b, ssrc, sdst);
  k_agg4<<<NB_AGG, 256, 0, stream>>>(row_off, csr_src, apc + 3 * (size_t)ETOT, h3b, ssrc,
                                     sdst, aggb);
  k_epi4<<<NB_N256, 256, 0, stream>>>(aggb, sm, b4, h4);

  // pooling head
  k_pool1<<<(NN * 64) / 256, 256, 0, stream>>>(h4, sidx, pool1);
  k_pool2<<<(MM * 64) / 256, 256, 0, stream>>>(pool1, snorm, nodes, pool2);
  k_final<<<GG, 64, 0, stream>>>(pool2, h4, dvi, Wp, Wt, Wo, bo, out);
}

// Round 5
// 703.229 us; speedup vs baseline: 1.3709x; 1.0353x over previous
//
#include <hip/hip_runtime.h>
#include <math.h>

#define NN 100000
#define EE 1600000
#define ETOT 1700000
#define MM 20000
#define GG 512

#define NBUCK 782   // ceil(100000/128)
#define NB1 256     // phase-1 blocks (must match k_bscan_a's 256 threads)
#define CAP 4096    // max edges per bucket held in LDS (expected 2174 +- 47)

static constexpr int NB_N256 = (NN + 255) / 256;    // 391
static constexpr int NB_E256 = (ETOT + 255) / 256;  // 6641
static constexpr int NB_AGG  = NN / 32;             // 3125

// small-buffer layout (float indices)
#define SM_MEAN 0
#define SM_WEA 16
#define SM_VS4 272
#define SM_VD4 400
#define SM_W4P 536
#define SM_TOTAL 8728

typedef unsigned long long ull;

__device__ __forceinline__ unsigned short f2bf(float f) {
  unsigned int u = __float_as_uint(f);
  u += 0x7fffu + ((u >> 16) & 1u);
  return (unsigned short)(u >> 16);
}
__device__ __forceinline__ float bf2f(unsigned int h) {
  return __uint_as_float(h << 16);
}
__device__ __forceinline__ float lrelu(float v, float s) { return v > 0.f ? v : s * v; }

// ---- precompute reduced weights ----
__global__ __launch_bounds__(256) void k_pre(
    float* __restrict__ sm, const float* __restrict__ We1, const float* __restrict__ We2,
    const float* __restrict__ We3, const float* __restrict__ We4,
    const float* __restrict__ ae1, const float* __restrict__ ae2,
    const float* __restrict__ ae3, const float* __restrict__ ae4,
    const float* __restrict__ as4, const float* __restrict__ ad4,
    const float* __restrict__ W4) {
  int t = threadIdx.x;
  {
    int l = t >> 6, d = (t >> 2) & 15, h = t & 3;
    const float* We = (l == 0) ? We1 : (l == 1) ? We2 : (l == 2) ? We3 : We4;
    const float* ae = (l == 0) ? ae1 : (l == 1) ? ae2 : (l == 2) ? ae3 : ae4;
    int C = (l == 3) ? 64 : 8;
    float s = 0.f;
    for (int c = 0; c < C; c++) s += We[d * (4 * C) + h * C + c] * ae[h * C + c];
    sm[SM_WEA + l * 64 + d * 4 + h] = s;
  }
  if (t < 128) {
    int k = t >> 2, h = t & 3;
    float s1 = 0.f, s2 = 0.f;
    for (int c = 0; c < 64; c++) {
      float w = W4[k * 256 + h * 64 + c];
      s1 += w * as4[h * 64 + c];
      s2 += w * ad4[h * 64 + c];
    }
    sm[SM_VS4 + t] = s1;
    sm[SM_VD4 + t] = s2;
  }
  for (int i = t; i < 8192; i += 256) {
    int row = i >> 6, c = i & 63;
    int h = row >> 5, k = row & 31;
    sm[SM_W4P + i] = 0.25f * W4[k * 256 + h * 64 + c];
  }
}

// ---- sort phase 1: per-block bucket histogram + fused ea dim-sum reduction ----
__global__ __launch_bounds__(1024) void k_hist1(const int* __restrict__ ei,
                                                const float* __restrict__ ea,
                                                int* __restrict__ blk_cnt,
                                                float* __restrict__ sm) {
  __shared__ int hist[NBUCK];
  __shared__ float lsum[16];
  int t = threadIdx.x;
  for (int i = t; i < NBUCK; i += 1024) hist[i] = 0;
  if (t < 16) lsum[t] = 0.f;
  __syncthreads();
  for (int e = blockIdx.x * 1024 + t; e < ETOT; e += NB1 * 1024) {
    int dst = (e < EE) ? ei[EE + e] : (e - EE);
    atomicAdd(&hist[dst >> 7], 1);
  }
  // fused ea column-sum: stride NB1*1024 is a multiple of 4, so (i&3) is fixed/thread
  {
    const float4* ea4 = (const float4*)ea;
    int q = t & 3;
    float4 a = make_float4(0.f, 0.f, 0.f, 0.f);
    for (size_t i = (size_t)blockIdx.x * 1024 + t; i < (size_t)EE * 4;
         i += (size_t)NB1 * 1024) {
      float4 v = ea4[i];
      a.x += v.x; a.y += v.y; a.z += v.z; a.w += v.w;
    }
    for (int m = 4; m < 64; m <<= 1) {
      a.x += __shfl_xor(a.x, m, 64);
      a.y += __shfl_xor(a.y, m, 64);
      a.z += __shfl_xor(a.z, m, 64);
      a.w += __shfl_xor(a.w, m, 64);
    }
    if ((t & 63) < 4) {
      atomicAdd(&lsum[q * 4 + 0], a.x);
      atomicAdd(&lsum[q * 4 + 1], a.y);
      atomicAdd(&lsum[q * 4 + 2], a.z);
      atomicAdd(&lsum[q * 4 + 3], a.w);
    }
  }
  __syncthreads();
  for (int i = t; i < NBUCK; i += 1024) blk_cnt[blockIdx.x * NBUCK + i] = hist[i];
  if (t < 16) atomicAdd(&sm[SM_MEAN + t], lsum[t]);
}

// ---- scan A: per-bucket exclusive scan over the 256 blocks ----
__global__ __launch_bounds__(256) void k_bscan_a(const int* __restrict__ blk_cnt,
                                                 int* __restrict__ blk_base_T,
                                                 int* __restrict__ bucket_tot) {
  __shared__ int s[256];
  int b = blockIdx.x, t = threadIdx.x;
  int v = blk_cnt[t * NBUCK + b];
  s[t] = v;
  __syncthreads();
  for (int off = 1; off < 256; off <<= 1) {
    int x = (t >= off) ? s[t - off] : 0;
    __syncthreads();
    s[t] += x;
    __syncthreads();
  }
  blk_base_T[b * 256 + t] = s[t] - v;
  if (t == 255) bucket_tot[b] = s[255];
}

// ---- scan B: exclusive scan of bucket totals ----
__global__ __launch_bounds__(1024) void k_bscan_b(const int* __restrict__ bucket_tot,
                                                  int* __restrict__ bucket_base,
                                                  int* __restrict__ row_off) {
  __shared__ int s[1024];
  int t = threadIdx.x;
  int v = (t < NBUCK) ? bucket_tot[t] : 0;
  s[t] = v;
  __syncthreads();
  for (int off = 1; off < 1024; off <<= 1) {
    int x = (t >= off) ? s[t - off] : 0;
    __syncthreads();
    s[t] += x;
    __syncthreads();
  }
  if (t < NBUCK) bucket_base[t] = s[t] - v;
  if (t == 0) {
    bucket_base[NBUCK] = ETOT;
    row_off[NN] = ETOT;
  }
}

// ---- sort phase 1 scatter: packed (src, eid|dstlow) into dense bucket regions ----
__global__ __launch_bounds__(1024) void k_scatter1(const int* __restrict__ ei,
                                                   const int* __restrict__ bucket_base,
                                                   const int* __restrict__ blk_base_T,
                                                   uint2* __restrict__ pairs) {
  __shared__ int base[NBUCK];
  __shared__ int rank[NBUCK];
  int t = threadIdx.x, blk = blockIdx.x;
  for (int i = t; i < NBUCK; i += 1024) {
    base[i] = bucket_base[i] + blk_base_T[i * 256 + blk];
    rank[i] = 0;
  }
  __syncthreads();
  for (int e = blk * 1024 + t; e < ETOT; e += NB1 * 1024) {
    int src, dst;
    if (e < EE) {
      src = ei[e];
      dst = ei[EE + e];
    } else {
      src = dst = e - EE;
    }
    int bin = dst >> 7;
    int r = atomicAdd(&rank[bin], 1);
    pairs[base[bin] + r] =
        make_uint2((unsigned)src, (unsigned)e | ((unsigned)(dst & 127) << 21));
  }
}

// ---- sort phase 2 (lean): LDS exact sort, coalesced csr_src + eidx writes ----
__global__ __launch_bounds__(256) void k_sort2(const uint2* __restrict__ pairs,
                                               const int* __restrict__ bucket_base,
                                               int* __restrict__ row_off,
                                               int* __restrict__ csr_src,
                                               int* __restrict__ eidx) {
  __shared__ uint2 plds[CAP];
  __shared__ unsigned short perm[CAP];
  __shared__ int hist[128];
  __shared__ int scan[128];
  __shared__ int rankv[128];
  int b = blockIdx.x, t = threadIdx.x;
  int start = bucket_base[b], end = bucket_base[b + 1];
  int cnt = end - start;
  if (t < 128) hist[t] = 0;
  __syncthreads();
  bool fits = (cnt <= CAP);
  if (fits) {
    for (int i = t; i < cnt; i += 256) {
      uint2 pe = pairs[start + i];
      plds[i] = pe;
      atomicAdd(&hist[(pe.y >> 21) & 127], 1);
    }
  } else {
    for (int i = t; i < cnt; i += 256)
      atomicAdd(&hist[(pairs[start + i].y >> 21) & 127], 1);
  }
  __syncthreads();
  if (t < 128) scan[t] = hist[t];
  __syncthreads();
  for (int off = 1; off < 128; off <<= 1) {
    int x = (t >= off && t < 128) ? scan[t - off] : 0;
    __syncthreads();
    if (t < 128) scan[t] += x;
    __syncthreads();
  }
  if (t < 128) {
    int excl = scan[t] - hist[t];
    rankv[t] = excl;
    int dst = b * 128 + t;
    if (dst < NN) row_off[dst] = start + excl;
  }
  __syncthreads();
  if (fits) {
    for (int i = t; i < cnt; i += 256) {
      int bin = (plds[i].y >> 21) & 127;
      int r = atomicAdd(&rankv[bin], 1);
      perm[r] = (unsigned short)i;
    }
    __syncthreads();
    for (int r = t; r < cnt; r += 256) {
      uint2 pe = plds[perm[r]];
      csr_src[start + r] = (int)pe.x;
      eidx[start + r] = (int)(pe.y & 0x1fffffu);
    }
  } else {
    for (int i = t; i < cnt; i += 256) {
      uint2 pe = pairs[start + i];
      int bin = (pe.y >> 21) & 127;
      int r = atomicAdd(&rankv[bin], 1);
      csr_src[start + r] = (int)pe.x;
      eidx[start + r] = (int)(pe.y & 0x1fffffu);
    }
  }
}

// ---- pack GEMV in CSR order: random 64B ea gather, all writes coalesced ----
__global__ __launch_bounds__(256) void k_pack(const int* __restrict__ eidx,
                                              const float* __restrict__ ea,
                                              const float* __restrict__ sm,
                                              ull* __restrict__ apc) {
  __shared__ float sWea[256];
  __shared__ float smean[16];
  int t = threadIdx.x;
  sWea[t] = sm[SM_WEA + t];
  if (t < 16) smean[t] = sm[SM_MEAN + t] * (1.f / EE);
  __syncthreads();
  int pos = blockIdx.x * 256 + t;
  if (pos >= ETOT) return;
  int eid = eidx[pos];
  float eav[16];
  if (eid < EE) {
    const float4* p = (const float4*)(ea + (size_t)eid * 16);
    float4 v0 = p[0], v1 = p[1], v2 = p[2], v3 = p[3];
    eav[0] = v0.x; eav[1] = v0.y; eav[2] = v0.z; eav[3] = v0.w;
    eav[4] = v1.x; eav[5] = v1.y; eav[6] = v1.z; eav[7] = v1.w;
    eav[8] = v2.x; eav[9] = v2.y; eav[10] = v2.z; eav[11] = v2.w;
    eav[12] = v3.x; eav[13] = v3.y; eav[14] = v3.z; eav[15] = v3.w;
  } else {
#pragma unroll
    for (int d = 0; d < 16; d++) eav[d] = smean[d];
  }
#pragma unroll
  for (int l = 0; l < 4; l++) {
    ull pk = 0;
#pragma unroll
    for (int h = 0; h < 4; h++) {
      float s = 0.f;
#pragma unroll
      for (int d = 0; d < 16; d++) s += eav[d] * sWea[l * 64 + d * 4 + h];
      pk |= (ull)f2bf(s) << (16 * h);
    }
    apc[(size_t)l * ETOT + pos] = pk;
  }
}

// ---- node transform: hx = in@W (bf16 out), alpha_src/dst reductions ----
template <int DIN>
__global__ __launch_bounds__(256) void k_t(const float* __restrict__ in,
                                           const float* __restrict__ W,
                                           const float* __restrict__ a_s,
                                           const float* __restrict__ a_d,
                                           unsigned short* __restrict__ hxb,
                                           float* __restrict__ ssrc,
                                           float* __restrict__ sdst) {
  __shared__ float4 sW[DIN * 8];
  __shared__ float sas[32], sad[32];
  int t = threadIdx.x;
  for (int i = t; i < DIN * 8; i += 256) sW[i] = ((const float4*)W)[i];
  if (t < 32) { sas[t] = a_s[t]; sad[t] = a_d[t]; }
  __syncthreads();
  int n = blockIdx.x * 256 + t;
  if (n >= NN) return;
  float acc[32];
#pragma unroll
  for (int j = 0; j < 32; j++) acc[j] = 0.f;
  const float* xr = in + (size_t)n * DIN;
  for (int k = 0; k < DIN; k += 4) {
    float4 xv = *(const float4*)(xr + k);
    float xa[4] = {xv.x, xv.y, xv.z, xv.w};
#pragma unroll
    for (int kk = 0; kk < 4; kk++) {
#pragma unroll
      for (int j4 = 0; j4 < 8; j4++) {
        float4 ww = sW[(k + kk) * 8 + j4];
        acc[j4 * 4 + 0] += xa[kk] * ww.x;
        acc[j4 * 4 + 1] += xa[kk] * ww.y;
        acc[j4 * 4 + 2] += xa[kk] * ww.z;
        acc[j4 * 4 + 3] += xa[kk] * ww.w;
      }
    }
  }
  float ssum[4], dsum[4];
#pragma unroll
  for (int h = 0; h < 4; h++) {
    float s = 0.f, d = 0.f;
#pragma unroll
    for (int c = 0; c < 8; c++) {
      s += acc[h * 8 + c] * sas[h * 8 + c];
      d += acc[h * 8 + c] * sad[h * 8 + c];
    }
    ssum[h] = s;
    dsum[h] = d;
  }
  unsigned int up[16];
#pragma unroll
  for (int i = 0; i < 16; i++)
    up[i] = (unsigned)f2bf(acc[2 * i]) | ((unsigned)f2bf(acc[2 * i + 1]) << 16);
  uint4* ho = (uint4*)(hxb + (size_t)n * 32);
  ho[0] = make_uint4(up[0], up[1], up[2], up[3]);
  ho[1] = make_uint4(up[4], up[5], up[6], up[7]);
  ho[2] = make_uint4(up[8], up[9], up[10], up[11]);
  ho[3] = make_uint4(up[12], up[13], up[14], up[15]);
  ((float4*)ssrc)[n] = make_float4(ssum[0], ssum[1], ssum[2], ssum[3]);
  ((float4*)sdst)[n] = make_float4(dsum[0], dsum[1], dsum[2], dsum[3]);
}

// ---- layer-4 attention reductions + bf16 copy of h3 ----
__global__ __launch_bounds__(256) void k_t4(const float* __restrict__ h3,
                                            const float* __restrict__ sm,
                                            unsigned short* __restrict__ h3b,
                                            float* __restrict__ ssrc,
                                            float* __restrict__ sdst) {
  __shared__ float sVs[128], sVd[128];
  int t = threadIdx.x;
  if (t < 128) { sVs[t] = sm[SM_VS4 + t]; sVd[t] = sm[SM_VD4 + t]; }
  __syncthreads();
  int n = blockIdx.x * 256 + t;
  if (n >= NN) return;
  const float* r = h3 + (size_t)n * 32;
  float v[32];
#pragma unroll
  for (int k = 0; k < 32; k++) v[k] = r[k];
  float s0 = 0, s1 = 0, s2 = 0, s3 = 0, d0 = 0, d1 = 0, d2 = 0, d3 = 0;
#pragma unroll
  for (int k = 0; k < 32; k++) {
    s0 += v[k] * sVs[k * 4 + 0]; s1 += v[k] * sVs[k * 4 + 1];
    s2 += v[k] * sVs[k * 4 + 2]; s3 += v[k] * sVs[k * 4 + 3];
    d0 += v[k] * sVd[k * 4 + 0]; d1 += v[k] * sVd[k * 4 + 1];
    d2 += v[k] * sVd[k * 4 + 2]; d3 += v[k] * sVd[k * 4 + 3];
  }
  unsigned int up[16];
#pragma unroll
  for (int i = 0; i < 16; i++)
    up[i] = (unsigned)f2bf(v[2 * i]) | ((unsigned)f2bf(v[2 * i + 1]) << 16);
  uint4* ho = (uint4*)(h3b + (size_t)n * 32);
  ho[0] = make_uint4(up[0], up[1], up[2], up[3]);
  ho[1] = make_uint4(up[4], up[5], up[6], up[7]);
  ho[2] = make_uint4(up[8], up[9], up[10], up[11]);
  ho[3] = make_uint4(up[12], up[13], up[14], up[15]);
  ((float4*)ssrc)[n] = make_float4(s0, s1, s2, s3);
  ((float4*)sdst)[n] = make_float4(d0, d1, d2, d3);
}

// ---- layers 1-3 aggregation: 8 lanes/node, no-max softmax (logits O(1)) ----
__global__ __launch_bounds__(256) void k_agg(const int* __restrict__ row_off,
                                             const int* __restrict__ csr_src,
                                             const ull* __restrict__ apl,
                                             const unsigned short* __restrict__ hxb,
                                             const float* __restrict__ ssrc,
                                             const float* __restrict__ sdst,
                                             const float* __restrict__ bias,
                                             float* __restrict__ outp) {
  int t = threadIdx.x;
  int g = t >> 3, j = t & 7, h = j >> 1;
  int n = blockIdx.x * 32 + g;
  if (n >= NN) return;
  float sd = sdst[n * 4 + h];
  int e0 = row_off[n], e1 = row_off[n + 1];
  float den = 0.f;
  float4 acc = make_float4(0.f, 0.f, 0.f, 0.f);
  for (int e = e0; e < e1; ++e) {
    int src = csr_src[e];
    ull pk = apl[e];
    float ae = bf2f((unsigned int)(unsigned short)(pk >> (16 * h)));
    float al = ssrc[src * 4 + h] + sd + ae;
    al = fminf(lrelu(al, 0.2f), 80.f);
    uint2 u = *(const uint2*)(hxb + (size_t)src * 32 + (j << 2));
    float p = __expf(al);
    den += p;
    acc.x += p * bf2f(u.x & 0xffffu);
    acc.y += p * bf2f(u.x >> 16);
    acc.z += p * bf2f(u.y & 0xffffu);
    acc.w += p * bf2f(u.y >> 16);
  }
  float inv = 1.f / (den + 1e-16f);
  float4 b = *(const float4*)(bias + (j << 2));
  float4 o;
  o.x = lrelu(acc.x * inv + b.x, 0.01f);
  o.y = lrelu(acc.y * inv + b.y, 0.01f);
  o.z = lrelu(acc.z * inv + b.z, 0.01f);
  o.w = lrelu(acc.w * inv + b.w, 0.01f);
  *(float4*)(outp + (size_t)n * 32 + (j << 2)) = o;
}

// ---- layer-4 aggregation: aggregate h3 per head, no-max softmax, bf16 out ----
__global__ __launch_bounds__(256) void k_agg4(const int* __restrict__ row_off,
                                              const int* __restrict__ csr_src,
                                              const ull* __restrict__ apl,
                                              const unsigned short* __restrict__ h3b,
                                              const float* __restrict__ ssrc,
                                              const float* __restrict__ sdst,
                                              unsigned short* __restrict__ aggb) {
  int t = threadIdx.x;
  int g = t >> 3, j = t & 7;
  int n = blockIdx.x * 32 + g;
  if (n >= NN) return;
  float4 sdv = ((const float4*)sdst)[n];
  float sda[4] = {sdv.x, sdv.y, sdv.z, sdv.w};
  int e0 = row_off[n], e1 = row_off[n + 1];
  float den[4];
  float4 acc[4];
#pragma unroll
  for (int h = 0; h < 4; h++) {
    den[h] = 0.f;
    acc[h] = make_float4(0.f, 0.f, 0.f, 0.f);
  }
  for (int e = e0; e < e1; ++e) {
    int src = csr_src[e];
    ull pk = apl[e];
    float4 ssv = ((const float4*)ssrc)[src];
    float ssa[4] = {ssv.x, ssv.y, ssv.z, ssv.w};
    uint2 u = *(const uint2*)(h3b + (size_t)src * 32 + (j << 2));
    float hx0 = bf2f(u.x & 0xffffu), hx1 = bf2f(u.x >> 16);
    float hx2 = bf2f(u.y & 0xffffu), hx3 = bf2f(u.y >> 16);
#pragma unroll
    for (int h = 0; h < 4; h++) {
      float al = ssa[h] + sda[h] + bf2f((unsigned int)(unsigned short)(pk >> (16 * h)));
      al = fminf(lrelu(al, 0.2f), 80.f);
      float p = __expf(al);
      den[h] += p;
      acc[h].x += p * hx0;
      acc[h].y += p * hx1;
      acc[h].z += p * hx2;
      acc[h].w += p * hx3;
    }
  }
#pragma unroll
  for (int h = 0; h < 4; h++) {
    float inv = 1.f / (den[h] + 1e-16f);
    unsigned int u0 = (unsigned)f2bf(acc[h].x * inv) | ((unsigned)f2bf(acc[h].y * inv) << 16);
    unsigned int u1 = (unsigned)f2bf(acc[h].z * inv) | ((unsigned)f2bf(acc[h].w * inv) << 16);
    *(uint2*)(aggb + (size_t)n * 128 + h * 32 + (j << 2)) = make_uint2(u0, u1);
  }
}

// ---- layer-4 epilogue: [N,128](bf16) @ W4p[128,64] + b4, lrelu -> h4 ----
__global__ __launch_bounds__(256) void k_epi4(const unsigned short* __restrict__ aggb,
                                              const float* __restrict__ sm,
                                              const float* __restrict__ b4,
                                              float* __restrict__ h4) {
  __shared__ float4 sW[2048];
  __shared__ float sb[64];
  int t = threadIdx.x;
  for (int i = t; i < 2048; i += 256) sW[i] = ((const float4*)(sm + SM_W4P))[i];
  if (t < 64) sb[t] = b4[t];
  __syncthreads();
  int n = blockIdx.x * 256 + t;
  if (n >= NN) return;
  float acc[64];
#pragma unroll
  for (int j = 0; j < 64; j++) acc[j] = 0.f;
  const unsigned short* r = aggb + (size_t)n * 128;
  for (int k = 0; k < 128; k += 4) {
    uint2 u = *(const uint2*)(r + k);
    float va[4] = {bf2f(u.x & 0xffffu), bf2f(u.x >> 16), bf2f(u.y & 0xffffu),
                   bf2f(u.y >> 16)};
#pragma unroll
    for (int kk = 0; kk < 4; kk++) {
#pragma unroll
      for (int j4 = 0; j4 < 16; j4++) {
        float4 wv = sW[(k + kk) * 16 + j4];
        acc[j4 * 4 + 0] += va[kk] * wv.x;
        acc[j4 * 4 + 1] += va[kk] * wv.y;
        acc[j4 * 4 + 2] += va[kk] * wv.z;
        acc[j4 * 4 + 3] += va[kk] * wv.w;
      }
    }
  }
  float* o = h4 + (size_t)n * 64;
#pragma unroll
  for (int j4 = 0; j4 < 16; j4++) {
    float4 ov;
    ov.x = lrelu(acc[j4 * 4 + 0] + sb[j4 * 4 + 0], 0.01f);
    ov.y = lrelu(acc[j4 * 4 + 1] + sb[j4 * 4 + 1], 0.01f);
    ov.z = lrelu(acc[j4 * 4 + 2] + sb[j4 * 4 + 2], 0.01f);
    ov.w = lrelu(acc[j4 * 4 + 3] + sb[j4 * 4 + 3], 0.01f);
    ((float4*)o)[j4] = ov;
  }
}

// ---- pooling ----
__global__ __launch_bounds__(256) void k_pool1(const float* __restrict__ h4,
                                               const int* __restrict__ sidx,
                                               float* __restrict__ pool1) {
  int i = blockIdx.x * 256 + threadIdx.x;
  if (i >= NN * 64) return;
  int n = i >> 6, c = i & 63;
  atomicAdd(&pool1[(size_t)sidx[n] * 64 + c], h4[i]);
}

__global__ __launch_bounds__(256) void k_pool2(const float* __restrict__ pool1,
                                               const float* __restrict__ snorm,
                                               const int* __restrict__ nodes,
                                               float* __restrict__ pool2) {
  int i = blockIdx.x * 256 + threadIdx.x;
  if (i >= MM * 64) return;
  int mi = i >> 6, c = i & 63;
  float v = pool1[i] / snorm[mi];
  atomicAdd(&pool2[(size_t)nodes[mi] * 64 + c], v);
}

// ---- final head: one wave per group ----
__global__ __launch_bounds__(64) void k_final(const float* __restrict__ pool2,
                                              const float* __restrict__ h4,
                                              const int* __restrict__ dvi,
                                              const float* __restrict__ Wp,
                                              const float* __restrict__ Wt,
                                              const float* __restrict__ Wo,
                                              const float* __restrict__ bo,
                                              float* __restrict__ out) {
  __shared__ float p[64], tt[64];
  int gI = blockIdx.x, j = threadIdx.x;
  p[j] = pool2[gI * 64 + j];
  tt[j] = h4[(size_t)dvi[gI] * 64 + j];
  __syncthreads();
  float f1 = 0.f, f2 = 0.f;
#pragma unroll 8
  for (int c = 0; c < 64; c++) {
    f1 += p[c] * Wp[c * 64 + j];
    f2 += tt[c] * Wt[c * 64 + j];
  }
  f1 = lrelu(f1, 0.01f);
  f2 = lrelu(f2, 0.01f);
  float v = f1 * Wo[j] + f2 * Wo[64 + j];
  for (int off = 32; off > 0; off >>= 1) v += __shfl_down(v, off, 64);
  if (j == 0) out[gI] = v + bo[0];
}

extern "C" void kernel_launch(void* const* d_in, const int* in_sizes, int n_in,
                              void* d_out, int out_size, void* d_ws, size_t ws_size,
                              hipStream_t stream) {
  const float* x = (const float*)d_in[0];
  const int* ei = (const int*)d_in[1];
  const float* ea = (const float*)d_in[2];
  const int* sidx = (const int*)d_in[3];
  const float* snorm = (const float*)d_in[4];
  const int* nodes = (const int*)d_in[5];
  const int* dvi = (const int*)d_in[6];
  const float* W1 = (const float*)d_in[7];
  const float* as1 = (const float*)d_in[9];
  const float* ad1 = (const float*)d_in[10];
  const float* b1 = (const float*)d_in[12];
  const float* W2 = (const float*)d_in[13];
  const float* as2 = (const float*)d_in[15];
  const float* ad2 = (const float*)d_in[16];
  const float* b2 = (const float*)d_in[18];
  const float* W3 = (const float*)d_in[19];
  const float* as3 = (const float*)d_in[21];
  const float* ad3 = (const float*)d_in[22];
  const float* b3 = (const float*)d_in[24];
  const float* b4 = (const float*)d_in[30];
  const float* Wp = (const float*)d_in[31];
  const float* Wt = (const float*)d_in[32];
  const float* Wo = (const float*)d_in[33];
  const float* bo = (const float*)d_in[34];
  float* out = (float*)d_out;

  char* w = (char*)d_ws;
  size_t off = 0;
  auto take = [&](size_t bytes) -> char* {
    char* p = w + off;
    off = (off + bytes + 255) & ~(size_t)255;
    return p;
  };
  int* row_off = (int*)take((size_t)(NN + 1) * 4);
  float* sm = (float*)take(SM_TOTAL * 4);
  uint2* pairs = (uint2*)take((size_t)ETOT * 8);
  int* csr_src = (int*)take((size_t)ETOT * 4);
  int* eidx = (int*)take((size_t)ETOT * 4);
  ull* apc = (ull*)take((size_t)ETOT * 4 * 8);
  int* blk_cnt = (int*)take((size_t)NB1 * NBUCK * 4);
  int* blk_base_T = (int*)take((size_t)NBUCK * NB1 * 4);
  int* bucket_tot = (int*)take((size_t)NBUCK * 4);
  int* bucket_base = (int*)take((size_t)(NBUCK + 1) * 4);
  float* h4 = (float*)take((size_t)NN * 64 * 4);
  unsigned short* aggb = (unsigned short*)take((size_t)NN * 128 * 2);
  unsigned short* hxb = (unsigned short*)take((size_t)NN * 32 * 2);
  unsigned short* h3b = (unsigned short*)take((size_t)NN * 32 * 2);
  float* ssrc = (float*)take((size_t)NN * 4 * 4);
  float* sdst = (float*)take((size_t)NN * 4 * 4);
  float* bufA = (float*)take((size_t)NN * 32 * 4);
  float* bufB = (float*)take((size_t)NN * 32 * 4);
  float* pool1 = (float*)take((size_t)MM * 64 * 4);
  float* pool2 = (float*)take((size_t)GG * 64 * 4);
  if (off > ws_size) return;  // workspace too small -> visible validation failure

  hipMemsetAsync(sm, 0, 64, stream);
  hipMemsetAsync(pool1, 0, (size_t)MM * 64 * 4, stream);
  hipMemsetAsync(pool2, 0, (size_t)GG * 64 * 4, stream);

  k_pre<<<1, 256, 0, stream>>>(sm, (const float*)d_in[8], (const float*)d_in[14],
                               (const float*)d_in[20], (const float*)d_in[26],
                               (const float*)d_in[11], (const float*)d_in[17],
                               (const float*)d_in[23], (const float*)d_in[29],
                               (const float*)d_in[27], (const float*)d_in[28],
                               (const float*)d_in[25]);

  // counting sort by dst (two-level, no global atomics); ea-mean fused in hist1
  k_hist1<<<NB1, 1024, 0, stream>>>(ei, ea, blk_cnt, sm);
  k_bscan_a<<<NBUCK, 256, 0, stream>>>(blk_cnt, blk_base_T, bucket_tot);
  k_bscan_b<<<1, 1024, 0, stream>>>(bucket_tot, bucket_base, row_off);
  k_scatter1<<<NB1, 1024, 0, stream>>>(ei, bucket_base, blk_base_T, pairs);
  k_sort2<<<NBUCK, 256, 0, stream>>>(pairs, bucket_base, row_off, csr_src, eidx);
  k_pack<<<NB_E256, 256, 0, stream>>>(eidx, ea, sm, apc);

  // layer 1
  k_t<64><<<NB_N256, 256, 0, stream>>>(x, W1, as1, ad1, hxb, ssrc, sdst);
  k_agg<<<NB_AGG, 256, 0, stream>>>(row_off, csr_src, apc, hxb, ssrc, sdst, b1, bufA);
  // layer 2
  k_t<32><<<NB_N256, 256, 0, stream>>>(bufA, W2, as2, ad2, hxb, ssrc, sdst);
  k_agg<<<NB_AGG, 256, 0, stream>>>(row_off, csr_src, apc + (size_t)ETOT, hxb, ssrc,
                                    sdst, b2, bufB);
  // layer 3
  k_t<32><<<NB_N256, 256, 0, stream>>>(bufB, W3, as3, ad3, hxb, ssrc, sdst);
  k_agg<<<NB_AGG, 256, 0, stream>>>(row_off, csr_src, apc + 2 * (size_t)ETOT, hxb, ssrc,
                                    sdst, b3, bufA);
  // layer 4
  k_t4<<<NB_N256, 256, 0, stream>>>(bufA, sm, h3b, ssrc, sdst);
  k_agg4<<<NB_AGG, 256, 0, stream>>>(row_off, csr_src, apc + 3 * (size_t)ETOT, h3b, ssrc,
                                     sdst, aggb);
  k_epi4<<<NB_N256, 256, 0, stream>>>(aggb, sm, b4, h4);

  // pooling head
  k_pool1<<<(NN * 64) / 256, 256, 0, stream>>>(h4, sidx, pool1);
  k_pool2<<<(MM * 64) / 256, 256, 0, stream>>>(pool1, snorm, nodes, pool2);
  k_final<<<GG, 64, 0, stream>>>(pool2, h4, dvi, Wp, Wt, Wo, bo, out);
}